// Round 1
// baseline (653.682 us; speedup 1.0000x reference)
//
#include <hip/hip_runtime.h>
#include <hip/hip_bf16.h>
#include <cstdint>
#include <cstddef>

// Problem constants
#define EE    1024
#define DIN   2048
#define NST   16
#define DTR   64
#define BB_   2
#define LL    1024
#define BL    (BB_*LL)        // 2048 tokens
#define NCHUNK 16
#define CLEN   64             // 1024 / 16

// ---------------- workspace layout (in floats) ----------------
// all offsets multiples of 16 floats -> 16B aligned given 256B-aligned d_ws
static constexpr size_t OFF_WIN  = 0;                        // 1024*4096
static constexpr size_t OFF_WX   = OFF_WIN  + 4194304;       // 2048*96
static constexpr size_t OFF_WDT  = OFF_WX   + 196608;        // 64*2048
static constexpr size_t OFF_WOUT = OFF_WDT  + 131072;        // 2048*1024
static constexpr size_t OFF_A2T  = OFF_WOUT + 2097152;       // 16*2048 (A transposed [n][d])
static constexpr size_t OFF_XZ   = OFF_A2T  + 32768;         // 2048*4096 ; later reused: dt (first half), ssm_out (second half)
static constexpr size_t OFF_Y    = OFF_XZ   + 8388608;       // 2048*2048
static constexpr size_t OFF_DTBC = OFF_Y    + 4194304;       // 2048*96
static constexpr size_t OFF_HC   = OFF_DTBC + 196608;        // 2*16*16*2048 carries [b][c][n][d]
static constexpr size_t OFF_SDT  = OFF_HC   + 1048576;       // 2*16*2048
// total = 20,545,536 floats = ~78.4 MB

// ---------------- TT weight materialization ----------------
// W[a*m2+b, i*n2+j] = sum_r g1[a,i,r] * g2[r,b,j];  W row-major (m1*m2) x (n1*n2)
__global__ void tt_build(const float* __restrict__ g1, const float* __restrict__ g2,
                         float* __restrict__ W,
                         int m1, int n1, int r, int m2, int n2)
{
    int idx = blockIdx.x * blockDim.x + threadIdx.x;
    int cols = n1 * n2;
    int total = m1 * m2 * cols;
    if (idx >= total) return;
    int row = idx / cols;
    int col = idx - row * cols;
    int a  = row / m2;
    int bb = row - a * m2;
    int i  = col / n2;
    int j  = col - i * n2;
    const float* g1p = g1 + (size_t)(a * n1 + i) * r;
    float s = 0.f;
    for (int rr = 0; rr < r; ++rr)
        s = fmaf(g1p[rr], g2[((size_t)rr * m2 + bb) * n2 + j], s);
    W[idx] = s;
}

// A2t[n][d] = -exp(A_log[d][n])
__global__ void prep_a2(const float* __restrict__ A_log, float* __restrict__ A2t)
{
    int idx = blockIdx.x * blockDim.x + threadIdx.x;
    if (idx >= DIN * NST) return;
    int d = idx >> 4, n = idx & 15;
    A2t[n * DIN + d] = -expf(A_log[idx]);
}

// ---------------- generic fp32 tiled GEMM ----------------
// C[M,N] = A[M,K(lda)] @ B[K,N(ldb)]; 64x64 tile, 4x4 per thread, BK=16.
// act: 0 = store, 1 = softplus+store, 2 = atomicAdd (split-K partial)
#define GBM 64
#define GBN 64
#define GBK 16

__device__ __forceinline__ float softplusf(float v) {
    return fmaxf(v, 0.f) + log1pf(__expf(-fabsf(v)));
}

__global__ __launch_bounds__(256) void gemm_f32(
    const float* __restrict__ A, const float* __restrict__ B, float* __restrict__ C,
    int M, int N, int K, int lda, int ldb, int ldc, int act, int kchunk)
{
    __shared__ float As[GBK][GBM];
    __shared__ float Bs[GBK][GBN];

    const int tid = threadIdx.x;
    const int tx4 = (tid & 15) * 4;
    const int ty4 = (tid >> 4) * 4;
    const int row0 = blockIdx.y * GBM;
    const int col0 = blockIdx.x * GBN;
    const int k_begin = blockIdx.z * kchunk;
    const int k_end   = min(K, k_begin + kchunk);

    // loader mappings
    const int lm  = tid >> 2;          // 0..63  A-tile row
    const int lk4 = (tid & 3) * 4;     // A-tile k offset (float4)
    const int lkb = tid >> 4;          // 0..15  B-tile k row
    const int ln4 = (tid & 15) * 4;    // B-tile n offset (float4)

    float acc[4][4] = {};

    for (int k0 = k_begin; k0 < k_end; k0 += GBK) {
        // A tile -> As[k][m]  (K assumed multiple of 16, M multiple of 64)
        {
            const float4 v = *(const float4*)(A + (size_t)(row0 + lm) * lda + k0 + lk4);
            As[lk4 + 0][lm] = v.x;
            As[lk4 + 1][lm] = v.y;
            As[lk4 + 2][lm] = v.z;
            As[lk4 + 3][lm] = v.w;
        }
        // B tile -> Bs[k][n]
        {
            const int col = col0 + ln4;
            float4 v;
            if (col + 4 <= N) {
                v = *(const float4*)(B + (size_t)(k0 + lkb) * ldb + col);
            } else {
                const float* bp = B + (size_t)(k0 + lkb) * ldb;
                v.x = (col + 0 < N) ? bp[col + 0] : 0.f;
                v.y = (col + 1 < N) ? bp[col + 1] : 0.f;
                v.z = (col + 2 < N) ? bp[col + 2] : 0.f;
                v.w = (col + 3 < N) ? bp[col + 3] : 0.f;
            }
            *(float4*)&Bs[lkb][ln4] = v;
        }
        __syncthreads();

        #pragma unroll
        for (int kk = 0; kk < GBK; ++kk) {
            const float4 av = *(const float4*)&As[kk][ty4];
            const float4 bv = *(const float4*)&Bs[kk][tx4];
            const float a0 = av.x, a1 = av.y, a2 = av.z, a3 = av.w;
            const float b0 = bv.x, b1 = bv.y, b2 = bv.z, b3 = bv.w;
            acc[0][0] = fmaf(a0, b0, acc[0][0]); acc[0][1] = fmaf(a0, b1, acc[0][1]);
            acc[0][2] = fmaf(a0, b2, acc[0][2]); acc[0][3] = fmaf(a0, b3, acc[0][3]);
            acc[1][0] = fmaf(a1, b0, acc[1][0]); acc[1][1] = fmaf(a1, b1, acc[1][1]);
            acc[1][2] = fmaf(a1, b2, acc[1][2]); acc[1][3] = fmaf(a1, b3, acc[1][3]);
            acc[2][0] = fmaf(a2, b0, acc[2][0]); acc[2][1] = fmaf(a2, b1, acc[2][1]);
            acc[2][2] = fmaf(a2, b2, acc[2][2]); acc[2][3] = fmaf(a2, b3, acc[2][3]);
            acc[3][0] = fmaf(a3, b0, acc[3][0]); acc[3][1] = fmaf(a3, b1, acc[3][1]);
            acc[3][2] = fmaf(a3, b2, acc[3][2]); acc[3][3] = fmaf(a3, b3, acc[3][3]);
        }
        __syncthreads();
    }

    #pragma unroll
    for (int i = 0; i < 4; ++i) {
        const int row = row0 + ty4 + i;
        #pragma unroll
        for (int j = 0; j < 4; ++j) {
            const int col = col0 + tx4 + j;
            if (col < N) {
                float v = acc[i][j];
                if (act == 2) {
                    atomicAdd(&C[(size_t)row * ldc + col], v);
                } else {
                    if (act == 1) v = softplusf(v);
                    C[(size_t)row * ldc + col] = v;
                }
            }
        }
    }
}

// ---------------- conv (depthwise, K=4, SAME: pad_lo=1) + SiLU + gate ----------------
// y[b,t,d] = silu( sum_k xz[b, t-1+k, d] * filt[k,d] + bias[d] ) * xz[b, t, DIN + d]
__global__ __launch_bounds__(256) void conv_gate(
    const float* __restrict__ xz, const float* __restrict__ filt,
    const float* __restrict__ bias, float* __restrict__ y)
{
    int idx = blockIdx.x * blockDim.x + threadIdx.x;   // over BL*DIN/4
    if (idx >= BL * DIN / 4) return;
    const int d  = (idx % (DIN / 4)) * 4;
    const int bt = idx / (DIN / 4);
    const int b  = bt >> 10;
    const int t  = bt & 1023;

    float4 acc = *(const float4*)(bias + d);
    #pragma unroll
    for (int k = 0; k < 4; ++k) {
        const int tt = t + k - 1;
        if ((unsigned)tt < (unsigned)LL) {
            const float4 xc = *(const float4*)(xz + (size_t)(b * LL + tt) * (2 * DIN) + d);
            const float4 f  = *(const float4*)(filt + (size_t)k * DIN + d);
            acc.x = fmaf(xc.x, f.x, acc.x);
            acc.y = fmaf(xc.y, f.y, acc.y);
            acc.z = fmaf(xc.z, f.z, acc.z);
            acc.w = fmaf(xc.w, f.w, acc.w);
        }
    }
    const float4 z = *(const float4*)(xz + (size_t)bt * (2 * DIN) + DIN + d);
    float4 out;
    out.x = acc.x / (1.f + __expf(-acc.x)) * z.x;
    out.y = acc.y / (1.f + __expf(-acc.y)) * z.y;
    out.z = acc.z / (1.f + __expf(-acc.z)) * z.z;
    out.w = acc.w / (1.f + __expf(-acc.w)) * z.w;
    *(float4*)(y + (size_t)bt * DIN + d) = out;
}

// ---------------- SSM chunked scan ----------------
// recurrence per (b,d,n): h = exp(dt*A[d,n]) * h + dt*B[t,n]*u ; y[t,d] = sum_n h*C[t,n] + D[d]*u
// Phase A: per (b, chunk, d): local scan from h=0 -> hend[b][c][n][d], sdt[b][c][d]
__global__ __launch_bounds__(256) void scan_phase_a(
    const float* __restrict__ dt, const float* __restrict__ u,
    const float* __restrict__ dtBC, const float* __restrict__ A2t,
    float* __restrict__ hend, float* __restrict__ sdtbuf)
{
    const int d = blockIdx.x * 256 + threadIdx.x;
    const int c = blockIdx.y;
    const int b = blockIdx.z;

    __shared__ float Bs[CLEN][NST];
    __shared__ float Cs[CLEN][NST];
    for (int e = threadIdx.x; e < CLEN * NST; e += 256) {
        const int tl = e >> 4, n = e & 15;
        const size_t base = (size_t)(b * LL + c * CLEN + tl) * 96;
        Bs[tl][n] = dtBC[base + 64 + n];
        Cs[tl][n] = dtBC[base + 80 + n];
    }
    __syncthreads();

    float A2r[NST];
    #pragma unroll
    for (int n = 0; n < NST; ++n) A2r[n] = A2t[n * DIN + d];

    float h[NST] = {};
    float sdt = 0.f;
    const size_t tbase = (size_t)(b * LL + c * CLEN) * DIN + d;
    for (int tl = 0; tl < CLEN; ++tl) {
        const float dtv = dt[tbase + (size_t)tl * DIN];
        const float uv  = u [tbase + (size_t)tl * DIN];
        sdt += dtv;
        const float cu = dtv * uv;
        #pragma unroll
        for (int n = 0; n < NST; ++n) {
            const float a = __expf(A2r[n] * dtv);
            h[n] = fmaf(a, h[n], cu * Bs[tl][n]);
        }
    }
    const int cb = b * NCHUNK + c;
    #pragma unroll
    for (int n = 0; n < NST; ++n)
        hend[((size_t)cb * NST + n) * DIN + d] = h[n];
    sdtbuf[(size_t)cb * DIN + d] = sdt;
}

// Phase B: scan the 16 chunk carries; in-place: hcarry becomes h-init per chunk
__global__ __launch_bounds__(256) void scan_phase_b(
    const float* __restrict__ A2t, const float* __restrict__ sdtbuf,
    float* __restrict__ hcarry)
{
    const int idx = blockIdx.x * 256 + threadIdx.x;  // b*32768 + n*2048 + d
    if (idx >= BB_ * NST * DIN) return;
    const int d = idx & (DIN - 1);
    const int n = (idx >> 11) & 15;
    const int b = idx >> 15;
    const float A2 = A2t[n * DIN + d];
    float h = 0.f;
    for (int c = 0; c < NCHUNK; ++c) {
        const int cb = b * NCHUNK + c;
        const size_t off = ((size_t)cb * NST + n) * DIN + d;
        const float he = hcarry[off];
        const float pa = __expf(A2 * sdtbuf[(size_t)cb * DIN + d]);
        hcarry[off] = h;                 // h entering chunk c
        h = fmaf(pa, h, he);
    }
}

// Phase C: replay with proper h-init, emit ys
__global__ __launch_bounds__(256) void scan_phase_c(
    const float* __restrict__ dt, const float* __restrict__ u,
    const float* __restrict__ dtBC, const float* __restrict__ A2t,
    const float* __restrict__ hinit, const float* __restrict__ Dp,
    float* __restrict__ ys)
{
    const int d = blockIdx.x * 256 + threadIdx.x;
    const int c = blockIdx.y;
    const int b = blockIdx.z;

    __shared__ float Bs[CLEN][NST];
    __shared__ float Cs[CLEN][NST];
    for (int e = threadIdx.x; e < CLEN * NST; e += 256) {
        const int tl = e >> 4, n = e & 15;
        const size_t base = (size_t)(b * LL + c * CLEN + tl) * 96;
        Bs[tl][n] = dtBC[base + 64 + n];
        Cs[tl][n] = dtBC[base + 80 + n];
    }
    __syncthreads();

    float A2r[NST], h[NST];
    const int cb = b * NCHUNK + c;
    #pragma unroll
    for (int n = 0; n < NST; ++n) {
        A2r[n] = A2t[n * DIN + d];
        h[n]   = hinit[((size_t)cb * NST + n) * DIN + d];
    }
    const float Dv = Dp[d];

    const size_t tbase = (size_t)(b * LL + c * CLEN) * DIN + d;
    for (int tl = 0; tl < CLEN; ++tl) {
        const float dtv = dt[tbase + (size_t)tl * DIN];
        const float uv  = u [tbase + (size_t)tl * DIN];
        const float cu = dtv * uv;
        float yacc = 0.f;
        #pragma unroll
        for (int n = 0; n < NST; ++n) {
            const float a = __expf(A2r[n] * dtv);
            h[n] = fmaf(a, h[n], cu * Bs[tl][n]);
            yacc = fmaf(h[n], Cs[tl][n], yacc);
        }
        ys[tbase + (size_t)tl * DIN] = fmaf(Dv, uv, yacc);
    }
}

// ---------------- launcher ----------------
extern "C" void kernel_launch(void* const* d_in, const int* in_sizes, int n_in,
                              void* d_out, int out_size, void* d_ws, size_t ws_size,
                              hipStream_t stream)
{
    const float* x       = (const float*)d_in[0];
    const float* in_g1   = (const float*)d_in[1];
    const float* in_g2   = (const float*)d_in[2];
    const float* x_g1    = (const float*)d_in[3];
    const float* x_g2    = (const float*)d_in[4];
    const float* dt_g1   = (const float*)d_in[5];
    const float* dt_g2   = (const float*)d_in[6];
    const float* out_g1  = (const float*)d_in[7];
    const float* out_g2  = (const float*)d_in[8];
    const float* filt    = (const float*)d_in[9];
    const float* bias    = (const float*)d_in[10];
    const float* A_log   = (const float*)d_in[11];
    const float* Dp      = (const float*)d_in[12];

    float* ws    = (float*)d_ws;
    float* W_in  = ws + OFF_WIN;
    float* W_x   = ws + OFF_WX;
    float* W_dt  = ws + OFF_WDT;
    float* W_out = ws + OFF_WOUT;
    float* A2t   = ws + OFF_A2T;
    float* xz    = ws + OFF_XZ;
    float* dtb   = ws + OFF_XZ;             // reuse (xz dead after conv_gate)
    float* ssm   = ws + OFF_XZ + 4194304;   // reuse, second half
    float* y     = ws + OFF_Y;
    float* dtBC  = ws + OFF_DTBC;
    float* hc    = ws + OFF_HC;
    float* sdt   = ws + OFF_SDT;

    // 1) materialize TT weights + A
    tt_build<<<(4194304 + 255) / 256, 256, 0, stream>>>(in_g1, in_g2, W_in, 32, 64, 16, 32, 64);
    tt_build<<<(196608 + 255) / 256, 256, 0, stream>>>(x_g1, x_g2, W_x, 32, 8, 16, 64, 12);
    tt_build<<<(131072 + 255) / 256, 256, 0, stream>>>(dt_g1, dt_g2, W_dt, 8, 32, 16, 8, 64);
    tt_build<<<(2097152 + 255) / 256, 256, 0, stream>>>(out_g1, out_g2, W_out, 32, 32, 16, 64, 32);
    prep_a2<<<(DIN * NST + 255) / 256, 256, 0, stream>>>(A_log, A2t);

    // 2) xz = x @ W_in   (2048 x 1024 x 4096)
    gemm_f32<<<dim3(4096 / GBN, BL / GBM, 1), 256, 0, stream>>>(
        x, W_in, xz, BL, 4096, 1024, 1024, 4096, 4096, 0, 1024);

    // 3) y = silu(conv(xc) + bias) * z
    conv_gate<<<(BL * DIN / 4 + 255) / 256, 256, 0, stream>>>(xz, filt, bias, y);

    // 4) dtBC = y @ W_x  (2048 x 2048 x 96), split-K=8 with atomicAdd
    hipMemsetAsync(dtBC, 0, (size_t)BL * 96 * sizeof(float), stream);
    gemm_f32<<<dim3(2, BL / GBM, 8), 256, 0, stream>>>(
        y, W_x, dtBC, BL, 96, 2048, 2048, 96, 96, 2, 256);

    // 5) dt = softplus(dt_un @ W_dt)  (2048 x 64 x 2048)  -> into dead xz region
    gemm_f32<<<dim3(DIN / GBN, BL / GBM, 1), 256, 0, stream>>>(
        dtBC, W_dt, dtb, BL, DIN, 64, 96, DIN, DIN, 1, 64);

    // 6) SSM chunked scan
    scan_phase_a<<<dim3(DIN / 256, NCHUNK, BB_), 256, 0, stream>>>(dtb, y, dtBC, A2t, hc, sdt);
    scan_phase_b<<<(BB_ * NST * DIN) / 256, 256, 0, stream>>>(A2t, sdt, hc);
    scan_phase_c<<<dim3(DIN / 256, NCHUNK, BB_), 256, 0, stream>>>(dtb, y, dtBC, A2t, hc, Dp, ssm);

    // 7) out = ssm_out @ W_out  (2048 x 2048 x 1024)
    gemm_f32<<<dim3(EE / GBN, BL / GBM, 1), 256, 0, stream>>>(
        ssm, W_out, (float*)d_out, BL, EE, 2048, 2048, EE, EE, 0, 2048);
}

// Round 2
// 520.519 us; speedup vs baseline: 1.2558x; 1.2558x over previous
//
#include <hip/hip_runtime.h>
#include <hip/hip_bf16.h>
#include <cstdint>
#include <cstddef>

// Problem constants
#define EE    1024
#define DIN   2048
#define NST   16
#define DTR   64
#define BB_   2
#define LL    1024
#define BL    (BB_*LL)        // 2048 tokens
#define NCHUNK 16
#define CLEN   64             // 1024 / 16

typedef unsigned short u16;
typedef unsigned int   u32;

// ---------------- workspace layout (in floats) ----------------
static constexpr size_t OFF_WINT  = 0;                         // bf16 [4096][1024]  -> 2,097,152 f
static constexpr size_t OFF_WX    = OFF_WINT  + 2097152;       // f32  [2048][96]    ->   196,608 f
static constexpr size_t OFF_WDT   = OFF_WX    + 196608;        // f32  [64][2048]... (built [96-pad? no] 64x2048) 131,072 f
static constexpr size_t OFF_WOUTT = OFF_WDT   + 131072;        // bf16 [1024][2048]  -> 1,048,576 f
static constexpr size_t OFF_A2T   = OFF_WOUTT + 1048576;       // f32  [16][2048]    ->    32,768 f
static constexpr size_t OFF_XB    = OFF_A2T   + 32768;         // bf16 [2048][1024]  -> 1,048,576 f
static constexpr size_t OFF_XZ    = OFF_XB    + 1048576;       // f32  [2048][4096]  -> 8,388,608 f (first half reused as dt)
static constexpr size_t OFF_Y     = OFF_XZ    + 8388608;       // f32  [2048][2048]  -> 4,194,304 f
static constexpr size_t OFF_YSB   = OFF_Y     + 4194304;       // bf16 [2048][2048]  -> 2,097,152 f
static constexpr size_t OFF_DTBC  = OFF_YSB   + 2097152;       // f32  [2048][96]    ->   196,608 f
static constexpr size_t OFF_HC    = OFF_DTBC  + 196608;        // f32  carries       -> 1,048,576 f
static constexpr size_t OFF_SDT   = OFF_HC    + 1048576;       // f32               ->     65,536 f
// total = 20,545,536 floats = ~78.4 MB (same footprint as round 1)

// ---------------- helpers ----------------
__device__ __forceinline__ u16 f2bf(float f) {   // RNE f32->bf16
    u32 u = __float_as_uint(f);
    u += 0x7fffu + ((u >> 16) & 1u);
    return (u16)(u >> 16);
}

__device__ __forceinline__ void async_copy16(const void* g, void* l) {
    __builtin_amdgcn_global_load_lds((const __attribute__((address_space(1))) u32*)g,
                                     (__attribute__((address_space(3))) u32*)l,
                                     16, 0, 0);
}

__device__ __forceinline__ float softplusf(float v) {
    return fmaxf(v, 0.f) + log1pf(__expf(-fabsf(v)));
}

// ---------------- TT weight materialization ----------------
// fp32 version: W[a*m2+bb, i*n2+j] = sum_r g1[a,i,r] * g2[r,bb,j]
__global__ void tt_build(const float* __restrict__ g1, const float* __restrict__ g2,
                         float* __restrict__ W,
                         int m1, int n1, int r, int m2, int n2)
{
    int idx = blockIdx.x * blockDim.x + threadIdx.x;
    int cols = n1 * n2;
    int total = m1 * m2 * cols;
    if (idx >= total) return;
    int row = idx / cols;
    int col = idx - row * cols;
    int a  = row / m2;
    int bb = row - a * m2;
    int i  = col / n2;
    int j  = col - i * n2;
    const float* g1p = g1 + (size_t)(a * n1 + i) * r;
    float s = 0.f;
    for (int rr = 0; rr < r; ++rr)
        s = fmaf(g1p[rr], g2[((size_t)rr * m2 + bb) * n2 + j], s);
    W[idx] = s;
}

// transposed bf16 version: Wt[c][k] = W[k][c], Wt is (n1*n2) x (m1*m2) bf16
__global__ void tt_build_t_bf16(const float* __restrict__ g1, const float* __restrict__ g2,
                                u16* __restrict__ Wt,
                                int m1, int n1, int r, int m2, int n2)
{
    int idx = blockIdx.x * blockDim.x + threadIdx.x;
    int rowsW = m1 * m2;
    int total = rowsW * n1 * n2;
    if (idx >= total) return;
    int c = idx / rowsW;            // W column  (Wt row)
    int k = idx - c * rowsW;        // W row     (Wt col) — fastest -> coalesced writes
    int a  = k / m2;
    int bb = k - a * m2;
    int i  = c / n2;
    int j  = c - i * n2;
    const float* g1p = g1 + (size_t)(a * n1 + i) * r;
    float s = 0.f;
    for (int rr = 0; rr < r; ++rr)
        s = fmaf(g1p[rr], g2[((size_t)rr * m2 + bb) * n2 + j], s);
    Wt[idx] = f2bf(s);
}

// A2t[n][d] = -exp(A_log[d][n])
__global__ void prep_a2(const float* __restrict__ A_log, float* __restrict__ A2t)
{
    int idx = blockIdx.x * blockDim.x + threadIdx.x;
    if (idx >= DIN * NST) return;
    int d = idx >> 4, n = idx & 15;
    A2t[n * DIN + d] = -expf(A_log[idx]);
}

// x (fp32) -> bf16, 4 elems/thread
__global__ void f32_to_bf16(const float* __restrict__ in, u16* __restrict__ out, int n4)
{
    int i = blockIdx.x * blockDim.x + threadIdx.x;
    if (i >= n4) return;
    float4 v = ((const float4*)in)[i];
    ushort4 o;
    o.x = f2bf(v.x); o.y = f2bf(v.y); o.z = f2bf(v.z); o.w = f2bf(v.w);
    ((ushort4*)out)[i] = o;
}

// ---------------- bf16 MFMA GEMM ----------------
// C[M,N] = A[M,K] @ Bt[N,K]^T, A/Bt row-major bf16, C fp32.
// BM=128, BN template (128 or 64). 256 threads = 4 waves in 2x2 grid,
// wave subtile 64 x (BN/2). BK=32, one 16x16x32 MFMA per (mt,nt) per k-step.
// LDS layout: [row][kslot] with XOR swizzle kq' = kq ^ ((row>>1)&3) on the
// 16B k-slots — keeps global_load_lds lane-contiguity (slot index == lane)
// while cutting ds_read_b128 conflicts from 8-way to 2-way (free).
typedef __attribute__((ext_vector_type(8))) short bf16x8;
typedef __attribute__((ext_vector_type(4))) float floatx4;

template<int BN>
__global__ __launch_bounds__(256) void gemm_bf16(
    const u16* __restrict__ A, const u16* __restrict__ Bt,
    float* __restrict__ C, int M, int N, int K, int ldc)
{
    constexpr int BM = 128;
    constexpr int NT = BN / 32;           // n-tiles per wave
    constexpr int NBCH = BN / 64;         // B staging insts per wave
    __shared__ u16 As[BM * 32];
    __shared__ u16 Bs[BN * 32];

    const int tid  = threadIdx.x;
    const int w    = tid >> 6;
    const int lane = tid & 63;
    const int wm   = w & 1, wn = w >> 1;
    const int row0 = blockIdx.y * BM;
    const int col0 = blockIdx.x * BN;

    // --- staging pointers (lane's global source; LDS dst is wave-uniform base) ---
    const int srow = lane >> 2;           // row within 16-row chunk
    const int kqp  = lane & 3;            // LDS k-slot (= lane order)
    const u16* ga[2];  u16* la[2];
    #pragma unroll
    for (int i = 0; i < 2; ++i) {
        const int c  = w * 2 + i;         // A chunk 0..7
        const int r  = c * 16 + srow;
        const int kq = kqp ^ ((r >> 1) & 3);
        ga[i] = A + (size_t)(row0 + r) * K + kq * 8;
        la[i] = &As[c * 512];
    }
    const u16* gb[NBCH];  u16* lb[NBCH];
    #pragma unroll
    for (int i = 0; i < NBCH; ++i) {
        const int c  = w * NBCH + i;      // B chunk
        const int r  = c * 16 + srow;
        const int kq = kqp ^ ((r >> 1) & 3);
        gb[i] = Bt + (size_t)(col0 + r) * K + kq * 8;
        lb[i] = &Bs[c * 512];
    }

    // --- ds_read element offsets (constant across k-steps) ---
    const int q = lane >> 4, l15 = lane & 15;
    int a_off[4], b_off[NT];
    #pragma unroll
    for (int mt = 0; mt < 4; ++mt) {
        const int r = wm * 64 + mt * 16 + l15;
        a_off[mt] = r * 32 + ((q ^ ((r >> 1) & 3)) * 8);
    }
    #pragma unroll
    for (int nt = 0; nt < NT; ++nt) {
        const int r = wn * (BN / 2) + nt * 16 + l15;
        b_off[nt] = r * 32 + ((q ^ ((r >> 1) & 3)) * 8);
    }

    floatx4 acc[4][NT];
    #pragma unroll
    for (int mt = 0; mt < 4; ++mt)
        #pragma unroll
        for (int nt = 0; nt < NT; ++nt)
            acc[mt][nt] = (floatx4){0.f, 0.f, 0.f, 0.f};

    for (int k0 = 0; k0 < K; k0 += 32) {
        #pragma unroll
        for (int i = 0; i < 2; ++i)    { async_copy16(ga[i], la[i]); ga[i] += 32; }
        #pragma unroll
        for (int i = 0; i < NBCH; ++i) { async_copy16(gb[i], lb[i]); gb[i] += 32; }
        __syncthreads();   // drains vmcnt -> LDS tiles ready

        bf16x8 af[4], bfv[NT];
        #pragma unroll
        for (int mt = 0; mt < 4; ++mt)  af[mt]  = *(const bf16x8*)&As[a_off[mt]];
        #pragma unroll
        for (int nt = 0; nt < NT; ++nt) bfv[nt] = *(const bf16x8*)&Bs[b_off[nt]];

        #pragma unroll
        for (int mt = 0; mt < 4; ++mt)
            #pragma unroll
            for (int nt = 0; nt < NT; ++nt)
                acc[mt][nt] = __builtin_amdgcn_mfma_f32_16x16x32_bf16(
                    af[mt], bfv[nt], acc[mt][nt], 0, 0, 0);

        __syncthreads();   // all reads done before next stage overwrites
    }

    // epilogue: C/D layout col=lane&15, row=(lane>>4)*4+reg  [verified m89/m91]
    #pragma unroll
    for (int mt = 0; mt < 4; ++mt) {
        const int row = row0 + wm * 64 + mt * 16 + q * 4;
        #pragma unroll
        for (int nt = 0; nt < NT; ++nt) {
            const int col = col0 + wn * (BN / 2) + nt * 16 + l15;
            float* cp = C + (size_t)row * ldc + col;
            #pragma unroll
            for (int r = 0; r < 4; ++r)
                cp[(size_t)r * ldc] = acc[mt][nt][r];
        }
    }
}

// ---------------- generic fp32 tiled GEMM (kept for GEMM2/GEMM3) ----------------
#define GBM 64
#define GBN 64
#define GBK 16

__global__ __launch_bounds__(256) void gemm_f32(
    const float* __restrict__ A, const float* __restrict__ B, float* __restrict__ C,
    int M, int N, int K, int lda, int ldb, int ldc, int act, int kchunk)
{
    __shared__ float As[GBK][GBM];
    __shared__ float Bs[GBK][GBN];

    const int tid = threadIdx.x;
    const int tx4 = (tid & 15) * 4;
    const int ty4 = (tid >> 4) * 4;
    const int row0 = blockIdx.y * GBM;
    const int col0 = blockIdx.x * GBN;
    const int k_begin = blockIdx.z * kchunk;
    const int k_end   = min(K, k_begin + kchunk);

    const int lm  = tid >> 2;
    const int lk4 = (tid & 3) * 4;
    const int lkb = tid >> 4;
    const int ln4 = (tid & 15) * 4;

    float acc[4][4] = {};

    for (int k0 = k_begin; k0 < k_end; k0 += GBK) {
        {
            const float4 v = *(const float4*)(A + (size_t)(row0 + lm) * lda + k0 + lk4);
            As[lk4 + 0][lm] = v.x;
            As[lk4 + 1][lm] = v.y;
            As[lk4 + 2][lm] = v.z;
            As[lk4 + 3][lm] = v.w;
        }
        {
            const int col = col0 + ln4;
            float4 v;
            if (col + 4 <= N) {
                v = *(const float4*)(B + (size_t)(k0 + lkb) * ldb + col);
            } else {
                const float* bp = B + (size_t)(k0 + lkb) * ldb;
                v.x = (col + 0 < N) ? bp[col + 0] : 0.f;
                v.y = (col + 1 < N) ? bp[col + 1] : 0.f;
                v.z = (col + 2 < N) ? bp[col + 2] : 0.f;
                v.w = (col + 3 < N) ? bp[col + 3] : 0.f;
            }
            *(float4*)&Bs[lkb][ln4] = v;
        }
        __syncthreads();

        #pragma unroll
        for (int kk = 0; kk < GBK; ++kk) {
            const float4 av = *(const float4*)&As[kk][ty4];
            const float4 bv = *(const float4*)&Bs[kk][tx4];
            const float a0 = av.x, a1 = av.y, a2 = av.z, a3 = av.w;
            const float b0 = bv.x, b1 = bv.y, b2 = bv.z, b3 = bv.w;
            acc[0][0] = fmaf(a0, b0, acc[0][0]); acc[0][1] = fmaf(a0, b1, acc[0][1]);
            acc[0][2] = fmaf(a0, b2, acc[0][2]); acc[0][3] = fmaf(a0, b3, acc[0][3]);
            acc[1][0] = fmaf(a1, b0, acc[1][0]); acc[1][1] = fmaf(a1, b1, acc[1][1]);
            acc[1][2] = fmaf(a1, b2, acc[1][2]); acc[1][3] = fmaf(a1, b3, acc[1][3]);
            acc[2][0] = fmaf(a2, b0, acc[2][0]); acc[2][1] = fmaf(a2, b1, acc[2][1]);
            acc[2][2] = fmaf(a2, b2, acc[2][2]); acc[2][3] = fmaf(a2, b3, acc[2][3]);
            acc[3][0] = fmaf(a3, b0, acc[3][0]); acc[3][1] = fmaf(a3, b1, acc[3][1]);
            acc[3][2] = fmaf(a3, b2, acc[3][2]); acc[3][3] = fmaf(a3, b3, acc[3][3]);
        }
        __syncthreads();
    }

    #pragma unroll
    for (int i = 0; i < 4; ++i) {
        const int row = row0 + ty4 + i;
        #pragma unroll
        for (int j = 0; j < 4; ++j) {
            const int col = col0 + tx4 + j;
            if (col < N) {
                float v = acc[i][j];
                if (act == 2) {
                    atomicAdd(&C[(size_t)row * ldc + col], v);
                } else {
                    if (act == 1) v = softplusf(v);
                    C[(size_t)row * ldc + col] = v;
                }
            }
        }
    }
}

// ---------------- conv (depthwise, K=4, SAME: pad_lo=1) + SiLU + gate ----------------
__global__ __launch_bounds__(256) void conv_gate(
    const float* __restrict__ xz, const float* __restrict__ filt,
    const float* __restrict__ bias, float* __restrict__ y)
{
    int idx = blockIdx.x * blockDim.x + threadIdx.x;
    if (idx >= BL * DIN / 4) return;
    const int d  = (idx % (DIN / 4)) * 4;
    const int bt = idx / (DIN / 4);
    const int b  = bt >> 10;
    const int t  = bt & 1023;

    float4 acc = *(const float4*)(bias + d);
    #pragma unroll
    for (int k = 0; k < 4; ++k) {
        const int tt = t + k - 1;
        if ((unsigned)tt < (unsigned)LL) {
            const float4 xc = *(const float4*)(xz + (size_t)(b * LL + tt) * (2 * DIN) + d);
            const float4 f  = *(const float4*)(filt + (size_t)k * DIN + d);
            acc.x = fmaf(xc.x, f.x, acc.x);
            acc.y = fmaf(xc.y, f.y, acc.y);
            acc.z = fmaf(xc.z, f.z, acc.z);
            acc.w = fmaf(xc.w, f.w, acc.w);
        }
    }
    const float4 z = *(const float4*)(xz + (size_t)bt * (2 * DIN) + DIN + d);
    float4 out;
    out.x = acc.x / (1.f + __expf(-acc.x)) * z.x;
    out.y = acc.y / (1.f + __expf(-acc.y)) * z.y;
    out.z = acc.z / (1.f + __expf(-acc.z)) * z.z;
    out.w = acc.w / (1.f + __expf(-acc.w)) * z.w;
    *(float4*)(y + (size_t)bt * DIN + d) = out;
}

// ---------------- SSM chunked scan ----------------
__global__ __launch_bounds__(256) void scan_phase_a(
    const float* __restrict__ dt, const float* __restrict__ u,
    const float* __restrict__ dtBC, const float* __restrict__ A2t,
    float* __restrict__ hend, float* __restrict__ sdtbuf)
{
    const int d = blockIdx.x * 256 + threadIdx.x;
    const int c = blockIdx.y;
    const int b = blockIdx.z;

    __shared__ float Bs[CLEN][NST];
    for (int e = threadIdx.x; e < CLEN * NST; e += 256) {
        const int tl = e >> 4, n = e & 15;
        Bs[tl][n] = dtBC[(size_t)(b * LL + c * CLEN + tl) * 96 + 64 + n];
    }
    __syncthreads();

    float A2r[NST];
    #pragma unroll
    for (int n = 0; n < NST; ++n) A2r[n] = A2t[n * DIN + d];

    float h[NST] = {};
    float sdt = 0.f;
    const size_t tbase = (size_t)(b * LL + c * CLEN) * DIN + d;
    for (int tl = 0; tl < CLEN; ++tl) {
        const float dtv = dt[tbase + (size_t)tl * DIN];
        const float uv  = u [tbase + (size_t)tl * DIN];
        sdt += dtv;
        const float cu = dtv * uv;
        #pragma unroll
        for (int n = 0; n < NST; ++n) {
            const float a = __expf(A2r[n] * dtv);
            h[n] = fmaf(a, h[n], cu * Bs[tl][n]);
        }
    }
    const int cb = b * NCHUNK + c;
    #pragma unroll
    for (int n = 0; n < NST; ++n)
        hend[((size_t)cb * NST + n) * DIN + d] = h[n];
    sdtbuf[(size_t)cb * DIN + d] = sdt;
}

__global__ __launch_bounds__(256) void scan_phase_b(
    const float* __restrict__ A2t, const float* __restrict__ sdtbuf,
    float* __restrict__ hcarry)
{
    const int idx = blockIdx.x * 256 + threadIdx.x;
    if (idx >= BB_ * NST * DIN) return;
    const int d = idx & (DIN - 1);
    const int n = (idx >> 11) & 15;
    const int b = idx >> 15;
    const float A2 = A2t[n * DIN + d];
    float h = 0.f;
    for (int c = 0; c < NCHUNK; ++c) {
        const int cb = b * NCHUNK + c;
        const size_t off = ((size_t)cb * NST + n) * DIN + d;
        const float he = hcarry[off];
        const float pa = __expf(A2 * sdtbuf[(size_t)cb * DIN + d]);
        hcarry[off] = h;
        h = fmaf(pa, h, he);
    }
}

// Phase C: replay with proper h-init, emit ys as bf16 (feeds gemm_bf16 GEMM4)
__global__ __launch_bounds__(256) void scan_phase_c(
    const float* __restrict__ dt, const float* __restrict__ u,
    const float* __restrict__ dtBC, const float* __restrict__ A2t,
    const float* __restrict__ hinit, const float* __restrict__ Dp,
    u16* __restrict__ ysb)
{
    const int d = blockIdx.x * 256 + threadIdx.x;
    const int c = blockIdx.y;
    const int b = blockIdx.z;

    __shared__ float Bs[CLEN][NST];
    __shared__ float Cs[CLEN][NST];
    for (int e = threadIdx.x; e < CLEN * NST; e += 256) {
        const int tl = e >> 4, n = e & 15;
        const size_t base = (size_t)(b * LL + c * CLEN + tl) * 96;
        Bs[tl][n] = dtBC[base + 64 + n];
        Cs[tl][n] = dtBC[base + 80 + n];
    }
    __syncthreads();

    float A2r[NST], h[NST];
    const int cb = b * NCHUNK + c;
    #pragma unroll
    for (int n = 0; n < NST; ++n) {
        A2r[n] = A2t[n * DIN + d];
        h[n]   = hinit[((size_t)cb * NST + n) * DIN + d];
    }
    const float Dv = Dp[d];

    const size_t tbase = (size_t)(b * LL + c * CLEN) * DIN + d;
    for (int tl = 0; tl < CLEN; ++tl) {
        const float dtv = dt[tbase + (size_t)tl * DIN];
        const float uv  = u [tbase + (size_t)tl * DIN];
        const float cu = dtv * uv;
        float yacc = 0.f;
        #pragma unroll
        for (int n = 0; n < NST; ++n) {
            const float a = __expf(A2r[n] * dtv);
            h[n] = fmaf(a, h[n], cu * Bs[tl][n]);
            yacc = fmaf(h[n], Cs[tl][n], yacc);
        }
        ysb[tbase + (size_t)tl * DIN] = f2bf(fmaf(Dv, uv, yacc));
    }
}

// ---------------- launcher ----------------
extern "C" void kernel_launch(void* const* d_in, const int* in_sizes, int n_in,
                              void* d_out, int out_size, void* d_ws, size_t ws_size,
                              hipStream_t stream)
{
    const float* x       = (const float*)d_in[0];
    const float* in_g1   = (const float*)d_in[1];
    const float* in_g2   = (const float*)d_in[2];
    const float* x_g1    = (const float*)d_in[3];
    const float* x_g2    = (const float*)d_in[4];
    const float* dt_g1   = (const float*)d_in[5];
    const float* dt_g2   = (const float*)d_in[6];
    const float* out_g1  = (const float*)d_in[7];
    const float* out_g2  = (const float*)d_in[8];
    const float* filt    = (const float*)d_in[9];
    const float* bias    = (const float*)d_in[10];
    const float* A_log   = (const float*)d_in[11];
    const float* Dp      = (const float*)d_in[12];

    float* ws     = (float*)d_ws;
    u16*   W_inT  = (u16*)(ws + OFF_WINT);
    float* W_x    = ws + OFF_WX;
    float* W_dt   = ws + OFF_WDT;
    u16*   W_outT = (u16*)(ws + OFF_WOUTT);
    float* A2t    = ws + OFF_A2T;
    u16*   xb     = (u16*)(ws + OFF_XB);
    float* xz     = ws + OFF_XZ;
    float* dtb    = ws + OFF_XZ;            // reuse (xz dead after conv_gate)
    float* y      = ws + OFF_Y;
    u16*   ysb    = (u16*)(ws + OFF_YSB);
    float* dtBC   = ws + OFF_DTBC;
    float* hc     = ws + OFF_HC;
    float* sdt    = ws + OFF_SDT;

    // 1) weights: W_in^T, W_out^T in bf16; W_x, W_dt fp32; A
    tt_build_t_bf16<<<(4194304 + 255) / 256, 256, 0, stream>>>(in_g1, in_g2, W_inT, 32, 64, 16, 32, 64);
    tt_build_t_bf16<<<(2097152 + 255) / 256, 256, 0, stream>>>(out_g1, out_g2, W_outT, 32, 32, 16, 64, 32);
    tt_build<<<(196608 + 255) / 256, 256, 0, stream>>>(x_g1, x_g2, W_x, 32, 8, 16, 64, 12);
    tt_build<<<(131072 + 255) / 256, 256, 0, stream>>>(dt_g1, dt_g2, W_dt, 8, 32, 16, 8, 64);
    prep_a2<<<(DIN * NST + 255) / 256, 256, 0, stream>>>(A_log, A2t);
    f32_to_bf16<<<(BL * EE / 4 + 255) / 256, 256, 0, stream>>>(x, xb, BL * EE / 4);

    // 2) xz = x @ W_in   (2048 x 4096 x 1024) — bf16 MFMA
    gemm_bf16<128><<<dim3(4096 / 128, BL / 128), 256, 0, stream>>>(
        xb, W_inT, xz, BL, 4096, EE, 4096);

    // 3) y = silu(conv(xc) + bias) * z
    conv_gate<<<(BL * DIN / 4 + 255) / 256, 256, 0, stream>>>(xz, filt, bias, y);

    // 4) dtBC = y @ W_x  (2048 x 96 x 2048), fp32 split-K=8 with atomicAdd
    hipMemsetAsync(dtBC, 0, (size_t)BL * 96 * sizeof(float), stream);
    gemm_f32<<<dim3(2, BL / GBM, 8), 256, 0, stream>>>(
        y, W_x, dtBC, BL, 96, 2048, 2048, 96, 96, 2, 256);

    // 5) dt = softplus(dt_un @ W_dt)  (2048 x 2048 x 64), fp32 -> dead xz region
    gemm_f32<<<dim3(DIN / GBN, BL / GBM, 1), 256, 0, stream>>>(
        dtBC, W_dt, dtb, BL, DIN, 64, 96, DIN, DIN, 1, 64);

    // 6) SSM chunked scan (phase C emits bf16)
    scan_phase_a<<<dim3(DIN / 256, NCHUNK, BB_), 256, 0, stream>>>(dtb, y, dtBC, A2t, hc, sdt);
    scan_phase_b<<<(BB_ * NST * DIN) / 256, 256, 0, stream>>>(A2t, sdt, hc);
    scan_phase_c<<<dim3(DIN / 256, NCHUNK, BB_), 256, 0, stream>>>(dtb, y, dtBC, A2t, hc, Dp, ysb);

    // 7) out = ssm @ W_out  (2048 x 1024 x 2048) — bf16 MFMA, BN=64 for 256 blocks
    gemm_bf16<64><<<dim3(EE / 64, BL / 128), 256, 0, stream>>>(
        ysb, W_outT, (float*)d_out, BL, EE, DIN, EE);
}

// Round 3
// 334.579 us; speedup vs baseline: 1.9537x; 1.5557x over previous
//
#include <hip/hip_runtime.h>
#include <hip/hip_bf16.h>
#include <cstdint>
#include <cstddef>

// Problem constants
#define EE    1024
#define DIN   2048
#define NST   16
#define DTR   64
#define BB_   2
#define LL    1024
#define BL    (BB_*LL)        // 2048 tokens
#define NCHUNK 16
#define CLEN   64             // 1024 / 16
#define RTT   16              // TT rank (all four factor pairs)

typedef unsigned short u16;
typedef unsigned int   u32;

// ---------------- workspace layout (in floats) ----------------
static constexpr size_t OFF_WINT  = 0;                         // bf16 [4096][1024]  -> 2,097,152 f
static constexpr size_t OFF_WX    = OFF_WINT  + 2097152;       // f32  [2048][96]    ->   196,608 f
static constexpr size_t OFF_WDT   = OFF_WX    + 196608;        // f32  [64][2048]    ->   131,072 f
static constexpr size_t OFF_WOUTT = OFF_WDT   + 131072;        // bf16 [1024][2048]  -> 1,048,576 f
static constexpr size_t OFF_A2T   = OFF_WOUTT + 1048576;       // f32  [16][2048]    ->    32,768 f
static constexpr size_t OFF_XB    = OFF_A2T   + 32768;         // bf16 [2048][1024]  -> 1,048,576 f
static constexpr size_t OFF_XZ    = OFF_XB    + 1048576;       // f32  [2048][4096]  -> 8,388,608 f (first half reused as dt)
static constexpr size_t OFF_Y     = OFF_XZ    + 8388608;       // f32  [2048][2048]  -> 4,194,304 f
static constexpr size_t OFF_YSB   = OFF_Y     + 4194304;       // bf16 [2048][2048]  -> 2,097,152 f
static constexpr size_t OFF_DTBC  = OFF_YSB   + 2097152;       // f32  [2048][96]    ->   196,608 f
static constexpr size_t OFF_HC    = OFF_DTBC  + 196608;        // f32  carries       -> 1,048,576 f
static constexpr size_t OFF_SDT   = OFF_HC    + 1048576;       // f32               ->     65,536 f
// total = 20,545,536 floats = ~78.4 MB

// ---------------- helpers ----------------
__device__ __forceinline__ u16 f2bf(float f) {   // RNE f32->bf16
    u32 u = __float_as_uint(f);
    u += 0x7fffu + ((u >> 16) & 1u);
    return (u16)(u >> 16);
}

__device__ __forceinline__ void async_copy16(const void* g, void* l) {
    __builtin_amdgcn_global_load_lds((const __attribute__((address_space(1))) u32*)g,
                                     (__attribute__((address_space(3))) u32*)l,
                                     16, 0, 0);
}

__device__ __forceinline__ float softplusf(float v) {
    return fmaxf(v, 0.f) + log1pf(__expf(-fabsf(v)));
}

// ---------------- TT weight materialization ----------------
// fp32 version (small W_x / W_dt): W[a*m2+bb, i*n2+j] = sum_r g1[a,i,r]*g2[r,bb,j]
__global__ void tt_build(const float* __restrict__ g1, const float* __restrict__ g2,
                         float* __restrict__ W,
                         int m1, int n1, int r, int m2, int n2)
{
    int idx = blockIdx.x * blockDim.x + threadIdx.x;
    int cols = n1 * n2;
    int total = m1 * m2 * cols;
    if (idx >= total) return;
    int row = idx / cols;
    int col = idx - row * cols;
    int a  = row / m2;
    int bb = row - a * m2;
    int i  = col / n2;
    int j  = col - i * n2;
    const float* g1p = g1 + (size_t)(a * n1 + i) * r;
    float s = 0.f;
    for (int rr = 0; rr < r; ++rr)
        s = fmaf(g1p[rr], g2[((size_t)rr * m2 + bb) * n2 + j], s);
    W[idx] = s;
}

// LDS-staged transposed bf16 build: one block per Wt row c = (i,j).
// Stages g1[.,i,.] and g2[.,.,j] into LDS (the old version's per-lane
// stride-n2 g2 reads were ~200-cycle latency-bound: 127 us for W_in).
// Compute reads are LDS broadcast / stride-1; writes are contiguous bf16.
__global__ __launch_bounds__(256) void tt_build_t_bf16_lds(
    const float* __restrict__ g1, const float* __restrict__ g2,
    u16* __restrict__ Wt, int m1, int n1, int m2, int n2)
{
    __shared__ float g1col[32 * RTT];     // [a][rr]   (m1 <= 32)
    __shared__ float g2col[RTT * 64];     // [rr][bb]  (m2 <= 64)

    const int c = blockIdx.x;             // 0 .. n1*n2-1
    const int i = c / n2;
    const int j = c - i * n2;
    const int rowsW = m1 * m2;

    for (int e = threadIdx.x; e < m1 * RTT; e += 256) {
        const int a = e / RTT, rr = e - a * RTT;
        g1col[e] = g1[(size_t)(a * n1 + i) * RTT + rr];
    }
    for (int e = threadIdx.x; e < RTT * m2; e += 256) {
        const int rr = e / m2, bb = e - rr * m2;
        g2col[e] = g2[(size_t)(rr * m2 + bb) * n2 + j];
    }
    __syncthreads();

    for (int k = threadIdx.x; k < rowsW; k += 256) {
        const int a  = k / m2;
        const int bb = k - a * m2;
        const float* gp = g1col + a * RTT;
        float s = 0.f;
        #pragma unroll
        for (int rr = 0; rr < RTT; ++rr)
            s = fmaf(gp[rr], g2col[rr * m2 + bb], s);
        Wt[(size_t)c * rowsW + k] = f2bf(s);
    }
}

// A2t[n][d] = -exp(A_log[d][n])
__global__ void prep_a2(const float* __restrict__ A_log, float* __restrict__ A2t)
{
    int idx = blockIdx.x * blockDim.x + threadIdx.x;
    if (idx >= DIN * NST) return;
    int d = idx >> 4, n = idx & 15;
    A2t[n * DIN + d] = -expf(A_log[idx]);
}

// x (fp32) -> bf16, 4 elems/thread
__global__ void f32_to_bf16(const float* __restrict__ in, u16* __restrict__ out, int n4)
{
    int i = blockIdx.x * blockDim.x + threadIdx.x;
    if (i >= n4) return;
    float4 v = ((const float4*)in)[i];
    ushort4 o;
    o.x = f2bf(v.x); o.y = f2bf(v.y); o.z = f2bf(v.z); o.w = f2bf(v.w);
    ((ushort4*)out)[i] = o;
}

// ---------------- bf16 MFMA GEMM ----------------
// C[M,N] = A[M,K] @ Bt[N,K]^T, A/Bt row-major bf16, C fp32.
// BM=128, BN template (128 or 64). 256 threads = 4 waves in 2x2 grid,
// wave subtile 64 x (BN/2). BK=32. XOR swizzle on 16B k-slots keeps
// global_load_lds lane-contiguity while making ds_read_b128 2-way (free).
typedef __attribute__((ext_vector_type(8))) short bf16x8;
typedef __attribute__((ext_vector_type(4))) float floatx4;

template<int BN>
__global__ __launch_bounds__(256) void gemm_bf16(
    const u16* __restrict__ A, const u16* __restrict__ Bt,
    float* __restrict__ C, int M, int N, int K, int ldc)
{
    constexpr int BM = 128;
    constexpr int NT = BN / 32;           // n-tiles per wave
    constexpr int NBCH = BN / 64;         // B staging insts per wave
    __shared__ u16 As[BM * 32];
    __shared__ u16 Bs[BN * 32];

    const int tid  = threadIdx.x;
    const int w    = tid >> 6;
    const int lane = tid & 63;
    const int wm   = w & 1, wn = w >> 1;
    const int row0 = blockIdx.y * BM;
    const int col0 = blockIdx.x * BN;

    const int srow = lane >> 2;           // row within 16-row chunk
    const int kqp  = lane & 3;            // LDS k-slot (= lane order)
    const u16* ga[2];  u16* la[2];
    #pragma unroll
    for (int i = 0; i < 2; ++i) {
        const int c  = w * 2 + i;
        const int r  = c * 16 + srow;
        const int kq = kqp ^ ((r >> 1) & 3);
        ga[i] = A + (size_t)(row0 + r) * K + kq * 8;
        la[i] = &As[c * 512];
    }
    const u16* gb[NBCH];  u16* lb[NBCH];
    #pragma unroll
    for (int i = 0; i < NBCH; ++i) {
        const int c  = w * NBCH + i;
        const int r  = c * 16 + srow;
        const int kq = kqp ^ ((r >> 1) & 3);
        gb[i] = Bt + (size_t)(col0 + r) * K + kq * 8;
        lb[i] = &Bs[c * 512];
    }

    const int q = lane >> 4, l15 = lane & 15;
    int a_off[4], b_off[NT];
    #pragma unroll
    for (int mt = 0; mt < 4; ++mt) {
        const int r = wm * 64 + mt * 16 + l15;
        a_off[mt] = r * 32 + ((q ^ ((r >> 1) & 3)) * 8);
    }
    #pragma unroll
    for (int nt = 0; nt < NT; ++nt) {
        const int r = wn * (BN / 2) + nt * 16 + l15;
        b_off[nt] = r * 32 + ((q ^ ((r >> 1) & 3)) * 8);
    }

    floatx4 acc[4][NT];
    #pragma unroll
    for (int mt = 0; mt < 4; ++mt)
        #pragma unroll
        for (int nt = 0; nt < NT; ++nt)
            acc[mt][nt] = (floatx4){0.f, 0.f, 0.f, 0.f};

    for (int k0 = 0; k0 < K; k0 += 32) {
        #pragma unroll
        for (int i = 0; i < 2; ++i)    { async_copy16(ga[i], la[i]); ga[i] += 32; }
        #pragma unroll
        for (int i = 0; i < NBCH; ++i) { async_copy16(gb[i], lb[i]); gb[i] += 32; }
        __syncthreads();

        bf16x8 af[4], bfv[NT];
        #pragma unroll
        for (int mt = 0; mt < 4; ++mt)  af[mt]  = *(const bf16x8*)&As[a_off[mt]];
        #pragma unroll
        for (int nt = 0; nt < NT; ++nt) bfv[nt] = *(const bf16x8*)&Bs[b_off[nt]];

        #pragma unroll
        for (int mt = 0; mt < 4; ++mt)
            #pragma unroll
            for (int nt = 0; nt < NT; ++nt)
                acc[mt][nt] = __builtin_amdgcn_mfma_f32_16x16x32_bf16(
                    af[mt], bfv[nt], acc[mt][nt], 0, 0, 0);

        __syncthreads();
    }

    // epilogue: C/D layout col=lane&15, row=(lane>>4)*4+reg  [verified m89/m91]
    #pragma unroll
    for (int mt = 0; mt < 4; ++mt) {
        const int row = row0 + wm * 64 + mt * 16 + q * 4;
        #pragma unroll
        for (int nt = 0; nt < NT; ++nt) {
            const int col = col0 + wn * (BN / 2) + nt * 16 + l15;
            float* cp = C + (size_t)row * ldc + col;
            #pragma unroll
            for (int r = 0; r < 4; ++r)
                cp[(size_t)r * ldc] = acc[mt][nt][r];
        }
    }
}

// ---------------- generic fp32 tiled GEMM (GEMM2/GEMM3) ----------------
#define GBM 64
#define GBN 64
#define GBK 16

__global__ __launch_bounds__(256) void gemm_f32(
    const float* __restrict__ A, const float* __restrict__ B, float* __restrict__ C,
    int M, int N, int K, int lda, int ldb, int ldc, int act, int kchunk)
{
    __shared__ float As[GBK][GBM];
    __shared__ float Bs[GBK][GBN];

    const int tid = threadIdx.x;
    const int tx4 = (tid & 15) * 4;
    const int ty4 = (tid >> 4) * 4;
    const int row0 = blockIdx.y * GBM;
    const int col0 = blockIdx.x * GBN;
    const int k_begin = blockIdx.z * kchunk;
    const int k_end   = min(K, k_begin + kchunk);

    const int lm  = tid >> 2;
    const int lk4 = (tid & 3) * 4;
    const int lkb = tid >> 4;
    const int ln4 = (tid & 15) * 4;

    float acc[4][4] = {};

    for (int k0 = k_begin; k0 < k_end; k0 += GBK) {
        {
            const float4 v = *(const float4*)(A + (size_t)(row0 + lm) * lda + k0 + lk4);
            As[lk4 + 0][lm] = v.x;
            As[lk4 + 1][lm] = v.y;
            As[lk4 + 2][lm] = v.z;
            As[lk4 + 3][lm] = v.w;
        }
        {
            const int col = col0 + ln4;
            float4 v;
            if (col + 4 <= N) {
                v = *(const float4*)(B + (size_t)(k0 + lkb) * ldb + col);
            } else {
                const float* bp = B + (size_t)(k0 + lkb) * ldb;
                v.x = (col + 0 < N) ? bp[col + 0] : 0.f;
                v.y = (col + 1 < N) ? bp[col + 1] : 0.f;
                v.z = (col + 2 < N) ? bp[col + 2] : 0.f;
                v.w = (col + 3 < N) ? bp[col + 3] : 0.f;
            }
            *(float4*)&Bs[lkb][ln4] = v;
        }
        __syncthreads();

        #pragma unroll
        for (int kk = 0; kk < GBK; ++kk) {
            const float4 av = *(const float4*)&As[kk][ty4];
            const float4 bv = *(const float4*)&Bs[kk][tx4];
            const float a0 = av.x, a1 = av.y, a2 = av.z, a3 = av.w;
            const float b0 = bv.x, b1 = bv.y, b2 = bv.z, b3 = bv.w;
            acc[0][0] = fmaf(a0, b0, acc[0][0]); acc[0][1] = fmaf(a0, b1, acc[0][1]);
            acc[0][2] = fmaf(a0, b2, acc[0][2]); acc[0][3] = fmaf(a0, b3, acc[0][3]);
            acc[1][0] = fmaf(a1, b0, acc[1][0]); acc[1][1] = fmaf(a1, b1, acc[1][1]);
            acc[1][2] = fmaf(a1, b2, acc[1][2]); acc[1][3] = fmaf(a1, b3, acc[1][3]);
            acc[2][0] = fmaf(a2, b0, acc[2][0]); acc[2][1] = fmaf(a2, b1, acc[2][1]);
            acc[2][2] = fmaf(a2, b2, acc[2][2]); acc[2][3] = fmaf(a2, b3, acc[2][3]);
            acc[3][0] = fmaf(a3, b0, acc[3][0]); acc[3][1] = fmaf(a3, b1, acc[3][1]);
            acc[3][2] = fmaf(a3, b2, acc[3][2]); acc[3][3] = fmaf(a3, b3, acc[3][3]);
        }
        __syncthreads();
    }

    #pragma unroll
    for (int i = 0; i < 4; ++i) {
        const int row = row0 + ty4 + i;
        #pragma unroll
        for (int j = 0; j < 4; ++j) {
            const int col = col0 + tx4 + j;
            if (col < N) {
                float v = acc[i][j];
                if (act == 2) {
                    atomicAdd(&C[(size_t)row * ldc + col], v);
                } else {
                    if (act == 1) v = softplusf(v);
                    C[(size_t)row * ldc + col] = v;
                }
            }
        }
    }
}

// ---------------- conv (depthwise, K=4, SAME: pad_lo=1) + SiLU + gate ----------------
__global__ __launch_bounds__(256) void conv_gate(
    const float* __restrict__ xz, const float* __restrict__ filt,
    const float* __restrict__ bias, float* __restrict__ y)
{
    int idx = blockIdx.x * blockDim.x + threadIdx.x;
    if (idx >= BL * DIN / 4) return;
    const int d  = (idx % (DIN / 4)) * 4;
    const int bt = idx / (DIN / 4);
    const int b  = bt >> 10;
    const int t  = bt & 1023;

    float4 acc = *(const float4*)(bias + d);
    #pragma unroll
    for (int k = 0; k < 4; ++k) {
        const int tt = t + k - 1;
        if ((unsigned)tt < (unsigned)LL) {
            const float4 xc = *(const float4*)(xz + (size_t)(b * LL + tt) * (2 * DIN) + d);
            const float4 f  = *(const float4*)(filt + (size_t)k * DIN + d);
            acc.x = fmaf(xc.x, f.x, acc.x);
            acc.y = fmaf(xc.y, f.y, acc.y);
            acc.z = fmaf(xc.z, f.z, acc.z);
            acc.w = fmaf(xc.w, f.w, acc.w);
        }
    }
    const float4 z = *(const float4*)(xz + (size_t)bt * (2 * DIN) + DIN + d);
    float4 out;
    out.x = acc.x / (1.f + __expf(-acc.x)) * z.x;
    out.y = acc.y / (1.f + __expf(-acc.y)) * z.y;
    out.z = acc.z / (1.f + __expf(-acc.z)) * z.z;
    out.w = acc.w / (1.f + __expf(-acc.w)) * z.w;
    *(float4*)(y + (size_t)bt * DIN + d) = out;
}

// ---------------- SSM chunked scan ----------------
__global__ __launch_bounds__(256) void scan_phase_a(
    const float* __restrict__ dt, const float* __restrict__ u,
    const float* __restrict__ dtBC, const float* __restrict__ A2t,
    float* __restrict__ hend, float* __restrict__ sdtbuf)
{
    const int d = blockIdx.x * 256 + threadIdx.x;
    const int c = blockIdx.y;
    const int b = blockIdx.z;

    __shared__ float Bs[CLEN][NST];
    for (int e = threadIdx.x; e < CLEN * NST; e += 256) {
        const int tl = e >> 4, n = e & 15;
        Bs[tl][n] = dtBC[(size_t)(b * LL + c * CLEN + tl) * 96 + 64 + n];
    }
    __syncthreads();

    float A2r[NST];
    #pragma unroll
    for (int n = 0; n < NST; ++n) A2r[n] = A2t[n * DIN + d];

    float h[NST] = {};
    float sdt = 0.f;
    const size_t tbase = (size_t)(b * LL + c * CLEN) * DIN + d;
    for (int tl = 0; tl < CLEN; ++tl) {
        const float dtv = dt[tbase + (size_t)tl * DIN];
        const float uv  = u [tbase + (size_t)tl * DIN];
        sdt += dtv;
        const float cu = dtv * uv;
        #pragma unroll
        for (int n = 0; n < NST; ++n) {
            const float a = __expf(A2r[n] * dtv);
            h[n] = fmaf(a, h[n], cu * Bs[tl][n]);
        }
    }
    const int cb = b * NCHUNK + c;
    #pragma unroll
    for (int n = 0; n < NST; ++n)
        hend[((size_t)cb * NST + n) * DIN + d] = h[n];
    sdtbuf[(size_t)cb * DIN + d] = sdt;
}

__global__ __launch_bounds__(256) void scan_phase_b(
    const float* __restrict__ A2t, const float* __restrict__ sdtbuf,
    float* __restrict__ hcarry)
{
    const int idx = blockIdx.x * 256 + threadIdx.x;
    if (idx >= BB_ * NST * DIN) return;
    const int d = idx & (DIN - 1);
    const int n = (idx >> 11) & 15;
    const int b = idx >> 15;
    const float A2 = A2t[n * DIN + d];
    float h = 0.f;
    for (int c = 0; c < NCHUNK; ++c) {
        const int cb = b * NCHUNK + c;
        const size_t off = ((size_t)cb * NST + n) * DIN + d;
        const float he = hcarry[off];
        const float pa = __expf(A2 * sdtbuf[(size_t)cb * DIN + d]);
        hcarry[off] = h;
        h = fmaf(pa, h, he);
    }
}

// Phase C: replay with proper h-init, emit ys as bf16 (feeds gemm_bf16 GEMM4)
__global__ __launch_bounds__(256) void scan_phase_c(
    const float* __restrict__ dt, const float* __restrict__ u,
    const float* __restrict__ dtBC, const float* __restrict__ A2t,
    const float* __restrict__ hinit, const float* __restrict__ Dp,
    u16* __restrict__ ysb)
{
    const int d = blockIdx.x * 256 + threadIdx.x;
    const int c = blockIdx.y;
    const int b = blockIdx.z;

    __shared__ float Bs[CLEN][NST];
    __shared__ float Cs[CLEN][NST];
    for (int e = threadIdx.x; e < CLEN * NST; e += 256) {
        const int tl = e >> 4, n = e & 15;
        const size_t base = (size_t)(b * LL + c * CLEN + tl) * 96;
        Bs[tl][n] = dtBC[base + 64 + n];
        Cs[tl][n] = dtBC[base + 80 + n];
    }
    __syncthreads();

    float A2r[NST], h[NST];
    const int cb = b * NCHUNK + c;
    #pragma unroll
    for (int n = 0; n < NST; ++n) {
        A2r[n] = A2t[n * DIN + d];
        h[n]   = hinit[((size_t)cb * NST + n) * DIN + d];
    }
    const float Dv = Dp[d];

    const size_t tbase = (size_t)(b * LL + c * CLEN) * DIN + d;
    for (int tl = 0; tl < CLEN; ++tl) {
        const float dtv = dt[tbase + (size_t)tl * DIN];
        const float uv  = u [tbase + (size_t)tl * DIN];
        const float cu = dtv * uv;
        float yacc = 0.f;
        #pragma unroll
        for (int n = 0; n < NST; ++n) {
            const float a = __expf(A2r[n] * dtv);
            h[n] = fmaf(a, h[n], cu * Bs[tl][n]);
            yacc = fmaf(h[n], Cs[tl][n], yacc);
        }
        ysb[tbase + (size_t)tl * DIN] = f2bf(fmaf(Dv, uv, yacc));
    }
}

// ---------------- launcher ----------------
extern "C" void kernel_launch(void* const* d_in, const int* in_sizes, int n_in,
                              void* d_out, int out_size, void* d_ws, size_t ws_size,
                              hipStream_t stream)
{
    const float* x       = (const float*)d_in[0];
    const float* in_g1   = (const float*)d_in[1];
    const float* in_g2   = (const float*)d_in[2];
    const float* x_g1    = (const float*)d_in[3];
    const float* x_g2    = (const float*)d_in[4];
    const float* dt_g1   = (const float*)d_in[5];
    const float* dt_g2   = (const float*)d_in[6];
    const float* out_g1  = (const float*)d_in[7];
    const float* out_g2  = (const float*)d_in[8];
    const float* filt    = (const float*)d_in[9];
    const float* bias    = (const float*)d_in[10];
    const float* A_log   = (const float*)d_in[11];
    const float* Dp      = (const float*)d_in[12];

    float* ws     = (float*)d_ws;
    u16*   W_inT  = (u16*)(ws + OFF_WINT);
    float* W_x    = ws + OFF_WX;
    float* W_dt   = ws + OFF_WDT;
    u16*   W_outT = (u16*)(ws + OFF_WOUTT);
    float* A2t    = ws + OFF_A2T;
    u16*   xb     = (u16*)(ws + OFF_XB);
    float* xz     = ws + OFF_XZ;
    float* dtb    = ws + OFF_XZ;            // reuse (xz dead after conv_gate)
    float* y      = ws + OFF_Y;
    u16*   ysb    = (u16*)(ws + OFF_YSB);
    float* dtBC   = ws + OFF_DTBC;
    float* hc     = ws + OFF_HC;
    float* sdt    = ws + OFF_SDT;

    // 1) weights: W_in^T, W_out^T bf16 via LDS-staged build; W_x, W_dt fp32; A
    tt_build_t_bf16_lds<<<64 * 64, 256, 0, stream>>>(in_g1, in_g2, W_inT, 32, 64, 32, 64);
    tt_build_t_bf16_lds<<<32 * 32, 256, 0, stream>>>(out_g1, out_g2, W_outT, 32, 32, 64, 32);
    tt_build<<<(196608 + 255) / 256, 256, 0, stream>>>(x_g1, x_g2, W_x, 32, 8, 16, 64, 12);
    tt_build<<<(131072 + 255) / 256, 256, 0, stream>>>(dt_g1, dt_g2, W_dt, 8, 32, 16, 8, 64);
    prep_a2<<<(DIN * NST + 255) / 256, 256, 0, stream>>>(A_log, A2t);
    f32_to_bf16<<<(BL * EE / 4 + 255) / 256, 256, 0, stream>>>(x, xb, BL * EE / 4);

    // 2) xz = x @ W_in   (2048 x 4096 x 1024) — bf16 MFMA
    gemm_bf16<128><<<dim3(4096 / 128, BL / 128), 256, 0, stream>>>(
        xb, W_inT, xz, BL, 4096, EE, 4096);

    // 3) y = silu(conv(xc) + bias) * z
    conv_gate<<<(BL * DIN / 4 + 255) / 256, 256, 0, stream>>>(xz, filt, bias, y);

    // 4) dtBC = y @ W_x  (2048 x 96 x 2048), fp32 split-K=8 with atomicAdd
    hipMemsetAsync(dtBC, 0, (size_t)BL * 96 * sizeof(float), stream);
    gemm_f32<<<dim3(2, BL / GBM, 8), 256, 0, stream>>>(
        y, W_x, dtBC, BL, 96, 2048, 2048, 96, 96, 2, 256);

    // 5) dt = softplus(dt_un @ W_dt)  (2048 x 2048 x 64), fp32 -> dead xz region
    gemm_f32<<<dim3(DIN / GBN, BL / GBM, 1), 256, 0, stream>>>(
        dtBC, W_dt, dtb, BL, DIN, 64, 96, DIN, DIN, 1, 64);

    // 6) SSM chunked scan (phase C emits bf16)
    scan_phase_a<<<dim3(DIN / 256, NCHUNK, BB_), 256, 0, stream>>>(dtb, y, dtBC, A2t, hc, sdt);
    scan_phase_b<<<(BB_ * NST * DIN) / 256, 256, 0, stream>>>(A2t, sdt, hc);
    scan_phase_c<<<dim3(DIN / 256, NCHUNK, BB_), 256, 0, stream>>>(dtb, y, dtBC, A2t, hc, Dp, ysb);

    // 7) out = ssm @ W_out  (2048 x 1024 x 2048) — bf16 MFMA, BN=64 for 256 blocks
    gemm_bf16<64><<<dim3(EE / 64, BL / 128), 256, 0, stream>>>(
        ysb, W_outT, (float*)d_out, BL, EE, DIN, EE);
}

// Round 4
// 300.108 us; speedup vs baseline: 2.1782x; 1.1149x over previous
//
#include <hip/hip_runtime.h>
#include <hip/hip_bf16.h>
#include <cstdint>
#include <cstddef>

// Problem constants
#define EE    1024
#define DIN   2048
#define NST   16
#define DTR   64
#define BB_   2
#define LL    1024
#define BL    (BB_*LL)        // 2048 tokens
#define NCHUNK 16
#define CLEN   64             // 1024 / 16
#define RTT   16              // TT rank (all four factor pairs)

typedef unsigned short u16;
typedef unsigned int   u32;

// ---------------- workspace layout (in floats) ----------------
// ws_size ~256 MiB (harness poison fill = 268 MB); we use ~86 MB.
static constexpr size_t OFF_WINT  = 0;                         // bf16 [4096][1024] -> 2,097,152 f
static constexpr size_t OFF_WOUTT = OFF_WINT  + 2097152;       // bf16 [1024][2048] -> 1,048,576 f
static constexpr size_t OFF_WXT   = OFF_WOUTT + 1048576;       // bf16 [128][2048]  ->   131,072 f (rows 96..127 zero)
static constexpr size_t OFF_WDTT  = OFF_WXT   + 131072;        // bf16 [2048][64]   ->    65,536 f
static constexpr size_t OFF_A2T   = OFF_WDTT  + 65536;         // f32  [16][2048]   ->    32,768 f
static constexpr size_t OFF_XB    = OFF_A2T   + 32768;         // bf16 [2048][1024] -> 1,048,576 f
static constexpr size_t OFF_XZ    = OFF_XB    + 1048576;       // f32  [2048][4096] -> 8,388,608 f (dt reuses first half)
static constexpr size_t OFF_YB    = OFF_XZ    + 8388608;       // bf16 [2048][2048] -> 2,097,152 f
static constexpr size_t OFF_PART  = OFF_YB    + 2097152;       // f32  [16][2048][128] -> 4,194,304 f
static constexpr size_t OFF_DTBC  = OFF_PART  + 4194304;       // f32  [2048][96]   ->   196,608 f
static constexpr size_t OFF_DTUNB = OFF_DTBC  + 196608;        // bf16 [2048][64]   ->    65,536 f
static constexpr size_t OFF_YSB   = OFF_DTUNB + 65536;         // bf16 [2048][2048] -> 2,097,152 f
static constexpr size_t OFF_HC    = OFF_YSB   + 2097152;       // f32  carries      -> 1,048,576 f
static constexpr size_t OFF_SDT   = OFF_HC    + 1048576;       // f32               ->    65,536 f

// ---------------- helpers ----------------
__device__ __forceinline__ u16 f2bf(float f) {   // RNE f32->bf16
    u32 u = __float_as_uint(f);
    u += 0x7fffu + ((u >> 16) & 1u);
    return (u16)(u >> 16);
}
__device__ __forceinline__ float bf2f(u16 v) {
    return __uint_as_float((u32)v << 16);
}

__device__ __forceinline__ void async_copy16(const void* g, void* l) {
    __builtin_amdgcn_global_load_lds((const __attribute__((address_space(1))) u32*)g,
                                     (__attribute__((address_space(3))) u32*)l,
                                     16, 0, 0);
}

__device__ __forceinline__ float softplusf(float v) {
    return fmaxf(v, 0.f) + log1pf(__expf(-fabsf(v)));
}

// ---------------- TT weight materialization (LDS-staged, transposed bf16) ----------------
// One block per Wt row c=(i,j). Stage g1[.,i,.] and g2[.,.,j] in LDS; outputs
// coalesced. Blocks with c >= crows write zeros (N-padding for GEMM2).
__global__ void tt_build_t_bf16_lds(
    const float* __restrict__ g1, const float* __restrict__ g2,
    u16* __restrict__ Wt, int m1, int n1, int m2, int n2, int crows)
{
    __shared__ float g1col[32 * RTT];     // [a][rr]   (m1 <= 32)
    __shared__ float g2col[RTT * 64];     // [rr][bb]  (m2 <= 64)

    const int c = blockIdx.x;
    const int rowsW = m1 * m2;
    if (c >= crows) {
        for (int k = threadIdx.x; k < rowsW; k += blockDim.x)
            Wt[(size_t)c * rowsW + k] = 0;
        return;
    }
    const int i = c / n2;
    const int j = c - i * n2;

    for (int e = threadIdx.x; e < m1 * RTT; e += blockDim.x) {
        const int a = e >> 4, rr = e & 15;
        g1col[e] = g1[(size_t)(a * n1 + i) * RTT + rr];
    }
    for (int e = threadIdx.x; e < RTT * m2; e += blockDim.x) {
        const int rr = e / m2, bb = e - rr * m2;
        g2col[e] = g2[(size_t)(rr * m2 + bb) * n2 + j];
    }
    __syncthreads();

    for (int k = threadIdx.x; k < rowsW; k += blockDim.x) {
        const int a  = k / m2;
        const int bb = k - a * m2;
        const float* gp = g1col + a * RTT;
        float s = 0.f;
        #pragma unroll
        for (int rr = 0; rr < RTT; ++rr)
            s = fmaf(gp[rr], g2col[rr * m2 + bb], s);
        Wt[(size_t)c * rowsW + k] = f2bf(s);
    }
}

// fused: x fp32 -> bf16 (float4 granularity) + A2t[n][d] = -exp(A_log[d][n])
__global__ void prep_misc(const float* __restrict__ x, u16* __restrict__ xb,
                          const float* __restrict__ A_log, float* __restrict__ A2t)
{
    int i = blockIdx.x * blockDim.x + threadIdx.x;
    if (i < BL * EE / 4) {
        float4 v = ((const float4*)x)[i];
        ushort4 o;
        o.x = f2bf(v.x); o.y = f2bf(v.y); o.z = f2bf(v.z); o.w = f2bf(v.w);
        ((ushort4*)xb)[i] = o;
    }
    if (i < DIN * NST) {
        int d = i >> 4, n = i & 15;
        A2t[n * DIN + d] = -expf(A_log[i]);
    }
}

// ---------------- bf16 MFMA GEMM ----------------
// C[.,.] = A[M,K] @ Bt[N,K]^T, A/Bt row-major bf16 (row stride = K), C fp32.
// BM=128, BN in {128,64}. 256 threads = 4 waves (2x2), wave tile 64 x BN/2.
// BK=32. XOR swizzle on 16B k-slots keeps global_load_lds lane-contiguity
// while making ds_read_b128 2-way (free, m136).
// Split-K: blockIdx.z selects k-chunk [z*kchunk, z*kchunk+kchunk) and output
// plane C + z*czstride. act: 0=store, 1=softplus+store.
typedef __attribute__((ext_vector_type(8))) short bf16x8;
typedef __attribute__((ext_vector_type(4))) float floatx4;

template<int BN>
__global__ __launch_bounds__(256) void gemm_bf16(
    const u16* __restrict__ A, const u16* __restrict__ Bt,
    float* __restrict__ C, int K, int ldc, int act, int kchunk, size_t czstride)
{
    constexpr int BM = 128;
    constexpr int NT = BN / 32;           // n-tiles per wave
    constexpr int NBCH = BN / 64;         // B staging insts per wave
    __shared__ u16 As[BM * 32];
    __shared__ u16 Bs[BN * 32];

    const int tid  = threadIdx.x;
    const int w    = tid >> 6;
    const int lane = tid & 63;
    const int wm   = w & 1, wn = w >> 1;
    const int row0 = blockIdx.y * BM;
    const int col0 = blockIdx.x * BN;
    const int kbeg = blockIdx.z * kchunk;

    const int srow = lane >> 2;           // row within 16-row chunk
    const int kqp  = lane & 3;            // LDS k-slot (= lane order)
    const u16* ga[2];  u16* la[2];
    #pragma unroll
    for (int i = 0; i < 2; ++i) {
        const int c  = w * 2 + i;
        const int r  = c * 16 + srow;
        const int kq = kqp ^ ((r >> 1) & 3);
        ga[i] = A + (size_t)(row0 + r) * K + kbeg + kq * 8;
        la[i] = &As[c * 512];
    }
    const u16* gb[NBCH];  u16* lb[NBCH];
    #pragma unroll
    for (int i = 0; i < NBCH; ++i) {
        const int c  = w * NBCH + i;
        const int r  = c * 16 + srow;
        const int kq = kqp ^ ((r >> 1) & 3);
        gb[i] = Bt + (size_t)(col0 + r) * K + kbeg + kq * 8;
        lb[i] = &Bs[c * 512];
    }

    const int q = lane >> 4, l15 = lane & 15;
    int a_off[4], b_off[NT];
    #pragma unroll
    for (int mt = 0; mt < 4; ++mt) {
        const int r = wm * 64 + mt * 16 + l15;
        a_off[mt] = r * 32 + ((q ^ ((r >> 1) & 3)) * 8);
    }
    #pragma unroll
    for (int nt = 0; nt < NT; ++nt) {
        const int r = wn * (BN / 2) + nt * 16 + l15;
        b_off[nt] = r * 32 + ((q ^ ((r >> 1) & 3)) * 8);
    }

    floatx4 acc[4][NT];
    #pragma unroll
    for (int mt = 0; mt < 4; ++mt)
        #pragma unroll
        for (int nt = 0; nt < NT; ++nt)
            acc[mt][nt] = (floatx4){0.f, 0.f, 0.f, 0.f};

    for (int k0 = 0; k0 < kchunk; k0 += 32) {
        #pragma unroll
        for (int i = 0; i < 2; ++i)    { async_copy16(ga[i], la[i]); ga[i] += 32; }
        #pragma unroll
        for (int i = 0; i < NBCH; ++i) { async_copy16(gb[i], lb[i]); gb[i] += 32; }
        __syncthreads();

        bf16x8 af[4], bfv[NT];
        #pragma unroll
        for (int mt = 0; mt < 4; ++mt)  af[mt]  = *(const bf16x8*)&As[a_off[mt]];
        #pragma unroll
        for (int nt = 0; nt < NT; ++nt) bfv[nt] = *(const bf16x8*)&Bs[b_off[nt]];

        #pragma unroll
        for (int mt = 0; mt < 4; ++mt)
            #pragma unroll
            for (int nt = 0; nt < NT; ++nt)
                acc[mt][nt] = __builtin_amdgcn_mfma_f32_16x16x32_bf16(
                    af[mt], bfv[nt], acc[mt][nt], 0, 0, 0);

        __syncthreads();
    }

    // epilogue: C/D layout col=lane&15, row=(lane>>4)*4+reg  [verified m89/m91]
    float* Cz = C + (size_t)blockIdx.z * czstride;
    #pragma unroll
    for (int mt = 0; mt < 4; ++mt) {
        const int row = row0 + wm * 64 + mt * 16 + q * 4;
        #pragma unroll
        for (int nt = 0; nt < NT; ++nt) {
            const int col = col0 + wn * (BN / 2) + nt * 16 + l15;
            float* cp = Cz + (size_t)row * ldc + col;
            #pragma unroll
            for (int r = 0; r < 4; ++r) {
                float v = acc[mt][nt][r];
                if (act == 1) v = softplusf(v);
                cp[(size_t)r * ldc] = v;
            }
        }
    }
}

// reduce split-K partials: dtBC[row][col<96] = sum_z part[z][row][col];
// also emit dt_un (cols 0..63) as bf16 for GEMM3.
__global__ __launch_bounds__(256) void reduce_dtbc(
    const float* __restrict__ part, float* __restrict__ dtBC, u16* __restrict__ dtun_b)
{
    int idx = blockIdx.x * 256 + threadIdx.x;
    if (idx >= BL * 96) return;
    const int row = idx / 96;
    const int col = idx - row * 96;
    float s = 0.f;
    #pragma unroll
    for (int z = 0; z < 16; ++z)
        s += part[(size_t)z * BL * 128 + (size_t)row * 128 + col];
    dtBC[idx] = s;
    if (col < 64) dtun_b[(size_t)row * 64 + col] = f2bf(s);
}

// ---------------- conv (depthwise, K=4, SAME: pad_lo=1) + SiLU + gate -> bf16 ----------------
__global__ __launch_bounds__(256) void conv_gate(
    const float* __restrict__ xz, const float* __restrict__ filt,
    const float* __restrict__ bias, u16* __restrict__ yb)
{
    int idx = blockIdx.x * blockDim.x + threadIdx.x;
    if (idx >= BL * DIN / 4) return;
    const int d  = (idx % (DIN / 4)) * 4;
    const int bt = idx / (DIN / 4);
    const int b  = bt >> 10;
    const int t  = bt & 1023;

    float4 acc = *(const float4*)(bias + d);
    #pragma unroll
    for (int k = 0; k < 4; ++k) {
        const int tt = t + k - 1;
        if ((unsigned)tt < (unsigned)LL) {
            const float4 xc = *(const float4*)(xz + (size_t)(b * LL + tt) * (2 * DIN) + d);
            const float4 f  = *(const float4*)(filt + (size_t)k * DIN + d);
            acc.x = fmaf(xc.x, f.x, acc.x);
            acc.y = fmaf(xc.y, f.y, acc.y);
            acc.z = fmaf(xc.z, f.z, acc.z);
            acc.w = fmaf(xc.w, f.w, acc.w);
        }
    }
    const float4 z = *(const float4*)(xz + (size_t)bt * (2 * DIN) + DIN + d);
    ushort4 o;
    o.x = f2bf(acc.x / (1.f + __expf(-acc.x)) * z.x);
    o.y = f2bf(acc.y / (1.f + __expf(-acc.y)) * z.y);
    o.z = f2bf(acc.z / (1.f + __expf(-acc.z)) * z.z);
    o.w = f2bf(acc.w / (1.f + __expf(-acc.w)) * z.w);
    *(ushort4*)(yb + (size_t)bt * DIN + d) = o;
}

// ---------------- SSM chunked scan (u in bf16) ----------------
__global__ __launch_bounds__(256) void scan_phase_a(
    const float* __restrict__ dt, const u16* __restrict__ u,
    const float* __restrict__ dtBC, const float* __restrict__ A2t,
    float* __restrict__ hend, float* __restrict__ sdtbuf)
{
    const int d = blockIdx.x * 256 + threadIdx.x;
    const int c = blockIdx.y;
    const int b = blockIdx.z;

    __shared__ float Bs[CLEN][NST];
    for (int e = threadIdx.x; e < CLEN * NST; e += 256) {
        const int tl = e >> 4, n = e & 15;
        Bs[tl][n] = dtBC[(size_t)(b * LL + c * CLEN + tl) * 96 + 64 + n];
    }
    __syncthreads();

    float A2r[NST];
    #pragma unroll
    for (int n = 0; n < NST; ++n) A2r[n] = A2t[n * DIN + d];

    float h[NST] = {};
    float sdt = 0.f;
    const size_t tbase = (size_t)(b * LL + c * CLEN) * DIN + d;
    for (int tl = 0; tl < CLEN; ++tl) {
        const float dtv = dt[tbase + (size_t)tl * DIN];
        const float uv  = bf2f(u[tbase + (size_t)tl * DIN]);
        sdt += dtv;
        const float cu = dtv * uv;
        #pragma unroll
        for (int n = 0; n < NST; ++n) {
            const float a = __expf(A2r[n] * dtv);
            h[n] = fmaf(a, h[n], cu * Bs[tl][n]);
        }
    }
    const int cb = b * NCHUNK + c;
    #pragma unroll
    for (int n = 0; n < NST; ++n)
        hend[((size_t)cb * NST + n) * DIN + d] = h[n];
    sdtbuf[(size_t)cb * DIN + d] = sdt;
}

__global__ __launch_bounds__(256) void scan_phase_b(
    const float* __restrict__ A2t, const float* __restrict__ sdtbuf,
    float* __restrict__ hcarry)
{
    const int idx = blockIdx.x * 256 + threadIdx.x;
    if (idx >= BB_ * NST * DIN) return;
    const int d = idx & (DIN - 1);
    const int n = (idx >> 11) & 15;
    const int b = idx >> 15;
    const float A2 = A2t[n * DIN + d];
    float h = 0.f;
    for (int c = 0; c < NCHUNK; ++c) {
        const int cb = b * NCHUNK + c;
        const size_t off = ((size_t)cb * NST + n) * DIN + d;
        const float he = hcarry[off];
        const float pa = __expf(A2 * sdtbuf[(size_t)cb * DIN + d]);
        hcarry[off] = h;
        h = fmaf(pa, h, he);
    }
}

__global__ __launch_bounds__(256) void scan_phase_c(
    const float* __restrict__ dt, const u16* __restrict__ u,
    const float* __restrict__ dtBC, const float* __restrict__ A2t,
    const float* __restrict__ hinit, const float* __restrict__ Dp,
    u16* __restrict__ ysb)
{
    const int d = blockIdx.x * 256 + threadIdx.x;
    const int c = blockIdx.y;
    const int b = blockIdx.z;

    __shared__ float Bs[CLEN][NST];
    __shared__ float Cs[CLEN][NST];
    for (int e = threadIdx.x; e < CLEN * NST; e += 256) {
        const int tl = e >> 4, n = e & 15;
        const size_t base = (size_t)(b * LL + c * CLEN + tl) * 96;
        Bs[tl][n] = dtBC[base + 64 + n];
        Cs[tl][n] = dtBC[base + 80 + n];
    }
    __syncthreads();

    float A2r[NST], h[NST];
    const int cb = b * NCHUNK + c;
    #pragma unroll
    for (int n = 0; n < NST; ++n) {
        A2r[n] = A2t[n * DIN + d];
        h[n]   = hinit[((size_t)cb * NST + n) * DIN + d];
    }
    const float Dv = Dp[d];

    const size_t tbase = (size_t)(b * LL + c * CLEN) * DIN + d;
    for (int tl = 0; tl < CLEN; ++tl) {
        const float dtv = dt[tbase + (size_t)tl * DIN];
        const float uv  = bf2f(u[tbase + (size_t)tl * DIN]);
        const float cu = dtv * uv;
        float yacc = 0.f;
        #pragma unroll
        for (int n = 0; n < NST; ++n) {
            const float a = __expf(A2r[n] * dtv);
            h[n] = fmaf(a, h[n], cu * Bs[tl][n]);
            yacc = fmaf(h[n], Cs[tl][n], yacc);
        }
        ysb[tbase + (size_t)tl * DIN] = f2bf(fmaf(Dv, uv, yacc));
    }
}

// ---------------- launcher ----------------
extern "C" void kernel_launch(void* const* d_in, const int* in_sizes, int n_in,
                              void* d_out, int out_size, void* d_ws, size_t ws_size,
                              hipStream_t stream)
{
    const float* x       = (const float*)d_in[0];
    const float* in_g1   = (const float*)d_in[1];
    const float* in_g2   = (const float*)d_in[2];
    const float* x_g1    = (const float*)d_in[3];
    const float* x_g2    = (const float*)d_in[4];
    const float* dt_g1   = (const float*)d_in[5];
    const float* dt_g2   = (const float*)d_in[6];
    const float* out_g1  = (const float*)d_in[7];
    const float* out_g2  = (const float*)d_in[8];
    const float* filt    = (const float*)d_in[9];
    const float* bias    = (const float*)d_in[10];
    const float* A_log   = (const float*)d_in[11];
    const float* Dp      = (const float*)d_in[12];

    float* ws     = (float*)d_ws;
    u16*   W_inT  = (u16*)(ws + OFF_WINT);
    u16*   W_outT = (u16*)(ws + OFF_WOUTT);
    u16*   W_xT   = (u16*)(ws + OFF_WXT);    // 128 x 2048, rows 96.. zero
    u16*   W_dtT  = (u16*)(ws + OFF_WDTT);   // 2048 x 64
    float* A2t    = ws + OFF_A2T;
    u16*   xb     = (u16*)(ws + OFF_XB);
    float* xz     = ws + OFF_XZ;
    float* dtb    = ws + OFF_XZ;             // reuse (xz dead after conv_gate)
    u16*   yb     = (u16*)(ws + OFF_YB);
    float* part   = ws + OFF_PART;
    float* dtBC   = ws + OFF_DTBC;
    u16*   dtun_b = (u16*)(ws + OFF_DTUNB);
    u16*   ysb    = (u16*)(ws + OFF_YSB);
    float* hc     = ws + OFF_HC;
    float* sdt    = ws + OFF_SDT;

    // 1) weights (all bf16, transposed) + misc prep
    tt_build_t_bf16_lds<<<4096, 256, 0, stream>>>(in_g1, in_g2, W_inT, 32, 64, 32, 64, 4096);
    tt_build_t_bf16_lds<<<1024, 256, 0, stream>>>(out_g1, out_g2, W_outT, 32, 32, 64, 32, 1024);
    tt_build_t_bf16_lds<<<128, 256, 0, stream>>>(x_g1, x_g2, W_xT, 32, 8, 64, 12, 96);
    tt_build_t_bf16_lds<<<2048, 64, 0, stream>>>(dt_g1, dt_g2, W_dtT, 8, 32, 8, 64, 2048);
    prep_misc<<<(BL * EE / 4 + 255) / 256, 256, 0, stream>>>(x, xb, A_log, A2t);

    // 2) xz = x @ W_in   (M=2048, N=4096, K=1024) — bf16 MFMA
    gemm_bf16<128><<<dim3(4096 / 128, BL / 128, 1), 256, 0, stream>>>(
        xb, W_inT, xz, EE, 4096, 0, EE, 0);

    // 3) y = silu(conv(xc) + bias) * z  -> bf16
    conv_gate<<<(BL * DIN / 4 + 255) / 256, 256, 0, stream>>>(xz, filt, bias, yb);

    // 4) dtBC partials = y @ W_x (M=2048, N=96->128, K=2048), split-K z=16
    gemm_bf16<128><<<dim3(1, BL / 128, 16), 256, 0, stream>>>(
        yb, W_xT, part, DIN, 128, 0, 128, (size_t)BL * 128);
    reduce_dtbc<<<(BL * 96 + 255) / 256, 256, 0, stream>>>(part, dtBC, dtun_b);

    // 5) dt = softplus(dt_un @ W_dt)  (M=2048, N=2048, K=64) — bf16 MFMA
    gemm_bf16<128><<<dim3(DIN / 128, BL / 128, 1), 256, 0, stream>>>(
        dtun_b, W_dtT, dtb, 64, DIN, 1, 64, 0);

    // 6) SSM chunked scan (u = yb bf16; phase C emits bf16)
    scan_phase_a<<<dim3(DIN / 256, NCHUNK, BB_), 256, 0, stream>>>(dtb, yb, dtBC, A2t, hc, sdt);
    scan_phase_b<<<(BB_ * NST * DIN) / 256, 256, 0, stream>>>(A2t, sdt, hc);
    scan_phase_c<<<dim3(DIN / 256, NCHUNK, BB_), 256, 0, stream>>>(dtb, yb, dtBC, A2t, hc, Dp, ysb);

    // 7) out = ssm @ W_out  (M=2048, N=1024, K=2048) — bf16 MFMA
    gemm_bf16<64><<<dim3(EE / 64, BL / 128, 1), 256, 0, stream>>>(
        ysb, W_outT, (float*)d_out, DIN, EE, 0, DIN, 0);
}

// Round 5
// 262.515 us; speedup vs baseline: 2.4901x; 1.1432x over previous
//
#include <hip/hip_runtime.h>
#include <hip/hip_bf16.h>
#include <cstdint>
#include <cstddef>

// Problem constants
#define EE    1024
#define DIN   2048
#define NST   16
#define DTR   64
#define BB_   2
#define LL    1024
#define BL    (BB_*LL)        // 2048 tokens
#define NCHUNK 16
#define CLEN   64             // 1024 / 16
#define RTT   16              // TT rank (all four factor pairs)

typedef unsigned short u16;
typedef unsigned int   u32;

// ---------------- workspace layout (in floats) ----------------
// harness ws = 256 MiB; we use ~82 MB.
static constexpr size_t OFF_WINT  = 0;                   // bf16 [4096][1024]
static constexpr size_t OFF_WOUTT = 2097152;             // bf16 [1024][2048]
static constexpr size_t OFF_WXT   = 3145728;             // bf16 [128][2048] rows>=96 zero
static constexpr size_t OFF_WDTT  = 3276800;             // bf16 [2048][64]
static constexpr size_t OFF_A2T   = 3342336;             // f32  [16][2048]
static constexpr size_t OFF_XB    = 3375104;             // bf16 [2048][1024]
static constexpr size_t OFF_XZB   = 4423680;             // bf16 [2048][4096]
static constexpr size_t OFF_YB    = 8617984;             // bf16 [2048][2048]
static constexpr size_t OFF_PART  = 10715136;            // f32  [16][2048][128]
static constexpr size_t OFF_DTBC  = 14909440;            // f32  [2048][96]
static constexpr size_t OFF_DTUNB = 15106048;            // bf16 [2048][64]
static constexpr size_t OFF_DTB   = 15171584;            // bf16 [2048][2048] (dt)
static constexpr size_t OFF_YSB   = 17268736;            // bf16 [2048][2048]
static constexpr size_t OFF_HC    = 19365888;            // f32  carries
static constexpr size_t OFF_SDT   = 20414464;            // f32  [2][16][2048]

// ---------------- helpers ----------------
__device__ __forceinline__ u16 f2bf(float f) {   // RNE f32->bf16
    u32 u = __float_as_uint(f);
    u += 0x7fffu + ((u >> 16) & 1u);
    return (u16)(u >> 16);
}
__device__ __forceinline__ float bf2f(u16 v) {
    return __uint_as_float((u32)v << 16);
}

__device__ __forceinline__ void async_copy16(const void* g, void* l) {
    __builtin_amdgcn_global_load_lds((const __attribute__((address_space(1))) u32*)g,
                                     (__attribute__((address_space(3))) u32*)l,
                                     16, 0, 0);
}

__device__ __forceinline__ float softplusf(float v) {
    return fmaxf(v, 0.f) + log1pf(__expf(-fabsf(v)));
}

// ---------------- fused prep: 4 TT builds + x->bf16 + A2t ----------------
// One block per Wt row c=(i,j); stages g1[.,i,.], g2[.,.,j] in LDS.
__device__ void tt_part(const float* __restrict__ g1, const float* __restrict__ g2,
                        u16* __restrict__ Wt, int m1, int n1, int m2, int n2,
                        int c, int crows, float* g1col, float* g2col)
{
    const int rowsW = m1 * m2;
    if (c >= crows) {                      // zero padding rows (GEMM2 N-pad)
        for (int k = threadIdx.x; k < rowsW; k += 256)
            Wt[(size_t)c * rowsW + k] = 0;
        return;
    }
    const int i = c / n2;
    const int j = c - i * n2;

    for (int e = threadIdx.x; e < m1 * RTT; e += 256) {
        const int a = e >> 4, rr = e & 15;
        g1col[e] = g1[(size_t)(a * n1 + i) * RTT + rr];
    }
    for (int e = threadIdx.x; e < RTT * m2; e += 256) {
        const int rr = e / m2, bb = e - rr * m2;
        g2col[e] = g2[(size_t)(rr * m2 + bb) * n2 + j];
    }
    __syncthreads();

    for (int k = threadIdx.x; k < rowsW; k += 256) {
        const int a  = k / m2;
        const int bb = k - a * m2;
        const float* gp = g1col + a * RTT;
        float s = 0.f;
        #pragma unroll
        for (int rr = 0; rr < RTT; ++rr)
            s = fmaf(gp[rr], g2col[rr * m2 + bb], s);
        Wt[(size_t)c * rowsW + k] = f2bf(s);
    }
}

__global__ __launch_bounds__(256) void mega_prep(
    const float* __restrict__ in_g1, const float* __restrict__ in_g2, u16* __restrict__ W_inT,
    const float* __restrict__ out_g1, const float* __restrict__ out_g2, u16* __restrict__ W_outT,
    const float* __restrict__ x_g1, const float* __restrict__ x_g2, u16* __restrict__ W_xT,
    const float* __restrict__ dt_g1, const float* __restrict__ dt_g2, u16* __restrict__ W_dtT,
    const float* __restrict__ x, u16* __restrict__ xb,
    const float* __restrict__ A_log, float* __restrict__ A2t)
{
    __shared__ float g1col[32 * RTT];
    __shared__ float g2col[RTT * 64];
    const int blk = blockIdx.x;
    if (blk < 4096) {
        tt_part(in_g1, in_g2, W_inT, 32, 64, 32, 64, blk, 4096, g1col, g2col);
    } else if (blk < 5120) {
        tt_part(out_g1, out_g2, W_outT, 32, 32, 64, 32, blk - 4096, 1024, g1col, g2col);
    } else if (blk < 5248) {
        tt_part(x_g1, x_g2, W_xT, 32, 8, 64, 12, blk - 5120, 96, g1col, g2col);
    } else if (blk < 7296) {
        tt_part(dt_g1, dt_g2, W_dtT, 8, 32, 8, 64, blk - 5248, 2048, g1col, g2col);
    } else if (blk < 9344) {
        const int i = (blk - 7296) * 256 + threadIdx.x;   // over BL*EE/4
        float4 v = ((const float4*)x)[i];
        ushort4 o;
        o.x = f2bf(v.x); o.y = f2bf(v.y); o.z = f2bf(v.z); o.w = f2bf(v.w);
        ((ushort4*)xb)[i] = o;
    } else {
        const int idx = (blk - 9344) * 256 + threadIdx.x; // over DIN*NST
        const int d = idx >> 4, n = idx & 15;
        A2t[n * DIN + d] = -expf(A_log[idx]);
    }
}

// ---------------- bf16 MFMA GEMM (templated BN / BK / output mode) ----------------
// C = A[M,K] @ Bt[N,K]^T. A/Bt row-major bf16 (row stride K). BM=128.
// BK in {32,64}: BK=64 halves barrier drains per MFMA (m97 stall).
// XOR swizzle on 16B k-slots: LDS pos s holds global slot s^((r>>1)&(SLOT-1))
// -> ds_read_b128 2-way (free, m136), global_load_lds lane-contiguity kept.
// OUT: 0 = f32 store (+split-K plane via czstride), 1 = bf16, 2 = softplus+bf16.
typedef __attribute__((ext_vector_type(8))) short bf16x8;
typedef __attribute__((ext_vector_type(4))) float floatx4;

template<int BN, int BK, int OUT>
__global__ __launch_bounds__(256) void gemm_bf16(
    const u16* __restrict__ A, const u16* __restrict__ Bt, void* __restrict__ Cout,
    int K, int ldc, int kchunk, size_t czstride)
{
    constexpr int BM   = 128;
    constexpr int NT   = BN / 32;          // n-tiles per wave
    constexpr int SLOT = BK / 8;           // 16B slots per LDS row
    constexpr int CR   = 64 / SLOT;        // rows per copy instruction
    constexpr int NACH = BM / CR / 4;      // A copies per wave
    constexpr int NBCH = BN / CR / 4;      // B copies per wave
    constexpr int KG   = BK / 32;          // MFMA k-groups per step
    __shared__ u16 As[BM * BK];
    __shared__ u16 Bs[BN * BK];

    const int tid  = threadIdx.x;
    const int w    = tid >> 6;
    const int lane = tid & 63;
    const int wm   = w & 1, wn = w >> 1;
    const int row0 = blockIdx.y * BM;
    const int col0 = blockIdx.x * BN;
    const int kbeg = blockIdx.z * kchunk;

    const int srow = lane / SLOT;
    const int kqp  = lane % SLOT;
    const u16* ga[NACH]; u16* la[NACH];
    #pragma unroll
    for (int i = 0; i < NACH; ++i) {
        const int c  = w * NACH + i;
        const int r  = c * CR + srow;
        const int kq = kqp ^ ((r >> 1) & (SLOT - 1));
        ga[i] = A + (size_t)(row0 + r) * K + kbeg + kq * 8;
        la[i] = &As[c * CR * BK];
    }
    const u16* gb[NBCH]; u16* lb[NBCH];
    #pragma unroll
    for (int i = 0; i < NBCH; ++i) {
        const int c  = w * NBCH + i;
        const int r  = c * CR + srow;
        const int kq = kqp ^ ((r >> 1) & (SLOT - 1));
        gb[i] = Bt + (size_t)(col0 + r) * K + kbeg + kq * 8;
        lb[i] = &Bs[c * CR * BK];
    }

    const int q = lane >> 4, l15 = lane & 15;
    int a_off[4][KG], b_off[NT][KG];
    #pragma unroll
    for (int mt = 0; mt < 4; ++mt) {
        const int r = wm * 64 + mt * 16 + l15;
        const int m = (r >> 1) & (SLOT - 1);
        #pragma unroll
        for (int kk = 0; kk < KG; ++kk)
            a_off[mt][kk] = r * BK + ((kk * 4 + q) ^ m) * 8;
    }
    #pragma unroll
    for (int nt = 0; nt < NT; ++nt) {
        const int r = wn * (BN / 2) + nt * 16 + l15;
        const int m = (r >> 1) & (SLOT - 1);
        #pragma unroll
        for (int kk = 0; kk < KG; ++kk)
            b_off[nt][kk] = r * BK + ((kk * 4 + q) ^ m) * 8;
    }

    floatx4 acc[4][NT];
    #pragma unroll
    for (int mt = 0; mt < 4; ++mt)
        #pragma unroll
        for (int nt = 0; nt < NT; ++nt)
            acc[mt][nt] = (floatx4){0.f, 0.f, 0.f, 0.f};

    for (int k0 = 0; k0 < kchunk; k0 += BK) {
        #pragma unroll
        for (int i = 0; i < NACH; ++i) { async_copy16(ga[i], la[i]); ga[i] += BK; }
        #pragma unroll
        for (int i = 0; i < NBCH; ++i) { async_copy16(gb[i], lb[i]); gb[i] += BK; }
        __syncthreads();   // drains vmcnt -> tiles ready

        bf16x8 af[4][KG], bfv[NT][KG];
        #pragma unroll
        for (int mt = 0; mt < 4; ++mt)
            #pragma unroll
            for (int kk = 0; kk < KG; ++kk)
                af[mt][kk] = *(const bf16x8*)&As[a_off[mt][kk]];
        #pragma unroll
        for (int nt = 0; nt < NT; ++nt)
            #pragma unroll
            for (int kk = 0; kk < KG; ++kk)
                bfv[nt][kk] = *(const bf16x8*)&Bs[b_off[nt][kk]];

        #pragma unroll
        for (int kk = 0; kk < KG; ++kk)
            #pragma unroll
            for (int mt = 0; mt < 4; ++mt)
                #pragma unroll
                for (int nt = 0; nt < NT; ++nt)
                    acc[mt][nt] = __builtin_amdgcn_mfma_f32_16x16x32_bf16(
                        af[mt][kk], bfv[nt][kk], acc[mt][nt], 0, 0, 0);

        __syncthreads();   // reads done before next stage overwrites
    }

    // epilogue: C/D layout col=lane&15, row=(lane>>4)*4+reg  [verified m89/m91]
    #pragma unroll
    for (int mt = 0; mt < 4; ++mt) {
        const int row = row0 + wm * 64 + mt * 16 + q * 4;
        #pragma unroll
        for (int nt = 0; nt < NT; ++nt) {
            const int col = col0 + wn * (BN / 2) + nt * 16 + l15;
            #pragma unroll
            for (int r = 0; r < 4; ++r) {
                const float v = acc[mt][nt][r];
                if constexpr (OUT == 0) {
                    ((float*)Cout)[(size_t)blockIdx.z * czstride + (size_t)(row + r) * ldc + col] = v;
                } else if constexpr (OUT == 1) {
                    ((u16*)Cout)[(size_t)(row + r) * ldc + col] = f2bf(v);
                } else {
                    ((u16*)Cout)[(size_t)(row + r) * ldc + col] = f2bf(softplusf(v));
                }
            }
        }
    }
}

// reduce split-K partials: dtBC[row][col<96] = sum_z part[z][row][col];
// also emit dt_un (cols 0..63) as bf16 for GEMM3.
__global__ __launch_bounds__(256) void reduce_dtbc(
    const float* __restrict__ part, float* __restrict__ dtBC, u16* __restrict__ dtun_b)
{
    int idx = blockIdx.x * 256 + threadIdx.x;
    if (idx >= BL * 96) return;
    const int row = idx / 96;
    const int col = idx - row * 96;
    float s = 0.f;
    #pragma unroll
    for (int z = 0; z < 16; ++z)
        s += part[(size_t)z * BL * 128 + (size_t)row * 128 + col];
    dtBC[idx] = s;
    if (col < 64) dtun_b[(size_t)row * 64 + col] = f2bf(s);
}

// ---------------- conv (depthwise K=4, SAME pad_lo=1) + SiLU + gate, bf16 in/out ----------------
__global__ __launch_bounds__(256) void conv_gate(
    const u16* __restrict__ xzb, const float* __restrict__ filt,
    const float* __restrict__ bias, u16* __restrict__ yb)
{
    int idx = blockIdx.x * blockDim.x + threadIdx.x;
    if (idx >= BL * DIN / 4) return;
    const int d  = (idx % (DIN / 4)) * 4;
    const int bt = idx / (DIN / 4);
    const int b  = bt >> 10;
    const int t  = bt & 1023;

    float4 acc = *(const float4*)(bias + d);
    #pragma unroll
    for (int k = 0; k < 4; ++k) {
        const int tt = t + k - 1;
        if ((unsigned)tt < (unsigned)LL) {
            const ushort4 xc = *(const ushort4*)(xzb + (size_t)(b * LL + tt) * (2 * DIN) + d);
            const float4 f  = *(const float4*)(filt + (size_t)k * DIN + d);
            acc.x = fmaf(bf2f(xc.x), f.x, acc.x);
            acc.y = fmaf(bf2f(xc.y), f.y, acc.y);
            acc.z = fmaf(bf2f(xc.z), f.z, acc.z);
            acc.w = fmaf(bf2f(xc.w), f.w, acc.w);
        }
    }
    const ushort4 z = *(const ushort4*)(xzb + (size_t)bt * (2 * DIN) + DIN + d);
    ushort4 o;
    o.x = f2bf(acc.x / (1.f + __expf(-acc.x)) * bf2f(z.x));
    o.y = f2bf(acc.y / (1.f + __expf(-acc.y)) * bf2f(z.y));
    o.z = f2bf(acc.z / (1.f + __expf(-acc.z)) * bf2f(z.z));
    o.w = f2bf(acc.w / (1.f + __expf(-acc.w)) * bf2f(z.w));
    *(ushort4*)(yb + (size_t)bt * DIN + d) = o;
}

// ---------------- SSM chunked scan (dt and u in bf16) ----------------
__global__ __launch_bounds__(256) void scan_phase_a(
    const u16* __restrict__ dt, const u16* __restrict__ u,
    const float* __restrict__ dtBC, const float* __restrict__ A2t,
    float* __restrict__ hend, float* __restrict__ sdtbuf)
{
    const int d = blockIdx.x * 256 + threadIdx.x;
    const int c = blockIdx.y;
    const int b = blockIdx.z;

    __shared__ float Bs[CLEN][NST];
    for (int e = threadIdx.x; e < CLEN * NST; e += 256) {
        const int tl = e >> 4, n = e & 15;
        Bs[tl][n] = dtBC[(size_t)(b * LL + c * CLEN + tl) * 96 + 64 + n];
    }
    __syncthreads();

    float A2r[NST];
    #pragma unroll
    for (int n = 0; n < NST; ++n) A2r[n] = A2t[n * DIN + d];

    float h[NST] = {};
    float sdt = 0.f;
    const size_t tbase = (size_t)(b * LL + c * CLEN) * DIN + d;
    for (int tl = 0; tl < CLEN; ++tl) {
        const float dtv = bf2f(dt[tbase + (size_t)tl * DIN]);
        const float uv  = bf2f(u [tbase + (size_t)tl * DIN]);
        sdt += dtv;
        const float cu = dtv * uv;
        #pragma unroll
        for (int n = 0; n < NST; ++n) {
            const float a = __expf(A2r[n] * dtv);
            h[n] = fmaf(a, h[n], cu * Bs[tl][n]);
        }
    }
    const int cb = b * NCHUNK + c;
    #pragma unroll
    for (int n = 0; n < NST; ++n)
        hend[((size_t)cb * NST + n) * DIN + d] = h[n];
    sdtbuf[(size_t)cb * DIN + d] = sdt;
}

__global__ __launch_bounds__(256) void scan_phase_b(
    const float* __restrict__ A2t, const float* __restrict__ sdtbuf,
    float* __restrict__ hcarry)
{
    const int idx = blockIdx.x * 256 + threadIdx.x;
    if (idx >= BB_ * NST * DIN) return;
    const int d = idx & (DIN - 1);
    const int n = (idx >> 11) & 15;
    const int b = idx >> 15;
    const float A2 = A2t[n * DIN + d];
    float h = 0.f;
    for (int c = 0; c < NCHUNK; ++c) {
        const int cb = b * NCHUNK + c;
        const size_t off = ((size_t)cb * NST + n) * DIN + d;
        const float he = hcarry[off];
        const float pa = __expf(A2 * sdtbuf[(size_t)cb * DIN + d]);
        hcarry[off] = h;
        h = fmaf(pa, h, he);
    }
}

__global__ __launch_bounds__(256) void scan_phase_c(
    const u16* __restrict__ dt, const u16* __restrict__ u,
    const float* __restrict__ dtBC, const float* __restrict__ A2t,
    const float* __restrict__ hinit, const float* __restrict__ Dp,
    u16* __restrict__ ysb)
{
    const int d = blockIdx.x * 256 + threadIdx.x;
    const int c = blockIdx.y;
    const int b = blockIdx.z;

    __shared__ float Bs[CLEN][NST];
    __shared__ float Cs[CLEN][NST];
    for (int e = threadIdx.x; e < CLEN * NST; e += 256) {
        const int tl = e >> 4, n = e & 15;
        const size_t base = (size_t)(b * LL + c * CLEN + tl) * 96;
        Bs[tl][n] = dtBC[base + 64 + n];
        Cs[tl][n] = dtBC[base + 80 + n];
    }
    __syncthreads();

    float A2r[NST], h[NST];
    const int cb = b * NCHUNK + c;
    #pragma unroll
    for (int n = 0; n < NST; ++n) {
        A2r[n] = A2t[n * DIN + d];
        h[n]   = hinit[((size_t)cb * NST + n) * DIN + d];
    }
    const float Dv = Dp[d];

    const size_t tbase = (size_t)(b * LL + c * CLEN) * DIN + d;
    for (int tl = 0; tl < CLEN; ++tl) {
        const float dtv = bf2f(dt[tbase + (size_t)tl * DIN]);
        const float uv  = bf2f(u [tbase + (size_t)tl * DIN]);
        const float cu = dtv * uv;
        float yacc = 0.f;
        #pragma unroll
        for (int n = 0; n < NST; ++n) {
            const float a = __expf(A2r[n] * dtv);
            h[n] = fmaf(a, h[n], cu * Bs[tl][n]);
            yacc = fmaf(h[n], Cs[tl][n], yacc);
        }
        ysb[tbase + (size_t)tl * DIN] = f2bf(fmaf(Dv, uv, yacc));
    }
}

// ---------------- launcher ----------------
extern "C" void kernel_launch(void* const* d_in, const int* in_sizes, int n_in,
                              void* d_out, int out_size, void* d_ws, size_t ws_size,
                              hipStream_t stream)
{
    const float* x       = (const float*)d_in[0];
    const float* in_g1   = (const float*)d_in[1];
    const float* in_g2   = (const float*)d_in[2];
    const float* x_g1    = (const float*)d_in[3];
    const float* x_g2    = (const float*)d_in[4];
    const float* dt_g1   = (const float*)d_in[5];
    const float* dt_g2   = (const float*)d_in[6];
    const float* out_g1  = (const float*)d_in[7];
    const float* out_g2  = (const float*)d_in[8];
    const float* filt    = (const float*)d_in[9];
    const float* bias    = (const float*)d_in[10];
    const float* A_log   = (const float*)d_in[11];
    const float* Dp      = (const float*)d_in[12];

    float* ws     = (float*)d_ws;
    u16*   W_inT  = (u16*)(ws + OFF_WINT);
    u16*   W_outT = (u16*)(ws + OFF_WOUTT);
    u16*   W_xT   = (u16*)(ws + OFF_WXT);
    u16*   W_dtT  = (u16*)(ws + OFF_WDTT);
    float* A2t    = ws + OFF_A2T;
    u16*   xb     = (u16*)(ws + OFF_XB);
    u16*   xzb    = (u16*)(ws + OFF_XZB);
    u16*   yb     = (u16*)(ws + OFF_YB);
    float* part   = ws + OFF_PART;
    float* dtBC   = ws + OFF_DTBC;
    u16*   dtun_b = (u16*)(ws + OFF_DTUNB);
    u16*   dtb    = (u16*)(ws + OFF_DTB);
    u16*   ysb    = (u16*)(ws + OFF_YSB);
    float* hc     = ws + OFF_HC;
    float* sdt    = ws + OFF_SDT;

    // 1) all prep in one launch: W_inT, W_outT, W_xT, W_dtT, x->bf16, A2t
    mega_prep<<<9472, 256, 0, stream>>>(
        in_g1, in_g2, W_inT, out_g1, out_g2, W_outT,
        x_g1, x_g2, W_xT, dt_g1, dt_g2, W_dtT,
        x, xb, A_log, A2t);

    // 2) xz = x @ W_in  (M=2048, N=4096, K=1024) -> bf16
    gemm_bf16<128, 32, 1><<<dim3(32, 16, 1), 256, 0, stream>>>(
        xb, W_inT, xzb, EE, 4096, EE, 0);

    // 3) y = silu(conv(xc) + bias) * z  -> bf16
    conv_gate<<<(BL * DIN / 4 + 255) / 256, 256, 0, stream>>>(xzb, filt, bias, yb);

    // 4) dtBC partials = y @ W_x (M=2048, N=128, K=2048), split-K z=16, BK=64
    gemm_bf16<128, 64, 0><<<dim3(1, 16, 16), 256, 0, stream>>>(
        yb, W_xT, part, DIN, 128, 128, (size_t)BL * 128);
    reduce_dtbc<<<(BL * 96 + 255) / 256, 256, 0, stream>>>(part, dtBC, dtun_b);

    // 5) dt = softplus(dt_un @ W_dt) (M=2048, N=2048, K=64) single-step -> bf16
    gemm_bf16<128, 64, 2><<<dim3(16, 16, 1), 256, 0, stream>>>(
        dtun_b, W_dtT, dtb, 64, DIN, 64, 0);

    // 6) SSM chunked scan (dt, u bf16; phase C emits bf16)
    scan_phase_a<<<dim3(DIN / 256, NCHUNK, BB_), 256, 0, stream>>>(dtb, yb, dtBC, A2t, hc, sdt);
    scan_phase_b<<<(BB_ * NST * DIN) / 256, 256, 0, stream>>>(A2t, sdt, hc);
    scan_phase_c<<<dim3(DIN / 256, NCHUNK, BB_), 256, 0, stream>>>(dtb, yb, dtBC, A2t, hc, Dp, ysb);

    // 7) out = ssm @ W_out (M=2048, N=1024, K=2048), BK=64 -> f32 d_out
    gemm_bf16<64, 64, 0><<<dim3(16, 16, 1), 256, 0, stream>>>(
        ysb, W_outT, (float*)d_out, DIN, EE, DIN, 0);
}

// Round 6
// 228.339 us; speedup vs baseline: 2.8628x; 1.1497x over previous
//
#include <hip/hip_runtime.h>
#include <hip/hip_bf16.h>
#include <cstdint>
#include <cstddef>

// Problem constants
#define EE    1024
#define DIN   2048
#define NST   16
#define DTR   64
#define BB_   2
#define LL    1024
#define BL    (BB_*LL)        // 2048 tokens
#define NCHUNK 32
#define CLEN   32             // 1024 / 32
#define RTT   16              // TT rank (all four factor pairs)

typedef unsigned short u16;
typedef unsigned int   u32;

// ---------------- workspace layout (in floats) ----------------
// harness ws = 256 MiB; we use ~86 MB.
static constexpr size_t OFF_WINT  = 0;                   // bf16 [4096][1024]
static constexpr size_t OFF_WOUTT = 2097152;             // bf16 [1024][2048]
static constexpr size_t OFF_WXT   = 3145728;             // bf16 [128][2048] rows>=96 zero
static constexpr size_t OFF_WDTT  = 3276800;             // bf16 [2048][64]
static constexpr size_t OFF_A2T   = 3342336;             // f32  [16][2048]
static constexpr size_t OFF_XB    = 3375104;             // bf16 [2048][1024]
static constexpr size_t OFF_XZB   = 4423680;             // bf16 [2048][4096]
static constexpr size_t OFF_YB    = 8617984;             // bf16 [2048][2048]
static constexpr size_t OFF_PART  = 10715136;            // f32  [16][2048][128] ; reused: GEMM4 partials [2][2048][1024]
static constexpr size_t OFF_DTBC  = 14909440;            // f32  [2048][96]
static constexpr size_t OFF_DTUNB = 15106048;            // bf16 [2048][64]
static constexpr size_t OFF_DTB   = 15171584;            // bf16 [2048][2048] (dt)
static constexpr size_t OFF_YSB   = 17268736;            // bf16 [2048][2048]
static constexpr size_t OFF_HC    = 19365888;            // f32  [2*32][16][2048] carries
static constexpr size_t OFF_SDT   = 21463040;            // f32  [2*32][2048]

// ---------------- helpers ----------------
__device__ __forceinline__ u16 f2bf(float f) {   // RNE f32->bf16
    u32 u = __float_as_uint(f);
    u += 0x7fffu + ((u >> 16) & 1u);
    return (u16)(u >> 16);
}
__device__ __forceinline__ float bf2f(u16 v) {
    return __uint_as_float((u32)v << 16);
}

__device__ __forceinline__ void async_copy16(const void* g, void* l) {
    __builtin_amdgcn_global_load_lds((const __attribute__((address_space(1))) u32*)g,
                                     (__attribute__((address_space(3))) u32*)l,
                                     16, 0, 0);
}

__device__ __forceinline__ float softplusf(float v) {
    return fmaxf(v, 0.f) + log1pf(__expf(-fabsf(v)));
}

// ---------------- fused prep: 4 TT builds + x->bf16 + A2t ----------------
__device__ void tt_part(const float* __restrict__ g1, const float* __restrict__ g2,
                        u16* __restrict__ Wt, int m1, int n1, int m2, int n2,
                        int c, int crows, float* g1col, float* g2col)
{
    const int rowsW = m1 * m2;
    if (c >= crows) {                      // zero padding rows (GEMM2 N-pad)
        for (int k = threadIdx.x; k < rowsW; k += 256)
            Wt[(size_t)c * rowsW + k] = 0;
        return;
    }
    const int i = c / n2;
    const int j = c - i * n2;

    for (int e = threadIdx.x; e < m1 * RTT; e += 256) {
        const int a = e >> 4, rr = e & 15;
        g1col[e] = g1[(size_t)(a * n1 + i) * RTT + rr];
    }
    for (int e = threadIdx.x; e < RTT * m2; e += 256) {
        const int rr = e / m2, bb = e - rr * m2;
        g2col[e] = g2[(size_t)(rr * m2 + bb) * n2 + j];
    }
    __syncthreads();

    for (int k = threadIdx.x; k < rowsW; k += 256) {
        const int a  = k / m2;
        const int bb = k - a * m2;
        const float* gp = g1col + a * RTT;
        float s = 0.f;
        #pragma unroll
        for (int rr = 0; rr < RTT; ++rr)
            s = fmaf(gp[rr], g2col[rr * m2 + bb], s);
        Wt[(size_t)c * rowsW + k] = f2bf(s);
    }
}

__global__ __launch_bounds__(256) void mega_prep(
    const float* __restrict__ in_g1, const float* __restrict__ in_g2, u16* __restrict__ W_inT,
    const float* __restrict__ out_g1, const float* __restrict__ out_g2, u16* __restrict__ W_outT,
    const float* __restrict__ x_g1, const float* __restrict__ x_g2, u16* __restrict__ W_xT,
    const float* __restrict__ dt_g1, const float* __restrict__ dt_g2, u16* __restrict__ W_dtT,
    const float* __restrict__ x, u16* __restrict__ xb,
    const float* __restrict__ A_log, float* __restrict__ A2t)
{
    __shared__ float g1col[32 * RTT];
    __shared__ float g2col[RTT * 64];
    const int blk = blockIdx.x;
    if (blk < 4096) {
        tt_part(in_g1, in_g2, W_inT, 32, 64, 32, 64, blk, 4096, g1col, g2col);
    } else if (blk < 5120) {
        tt_part(out_g1, out_g2, W_outT, 32, 32, 64, 32, blk - 4096, 1024, g1col, g2col);
    } else if (blk < 5248) {
        tt_part(x_g1, x_g2, W_xT, 32, 8, 64, 12, blk - 5120, 96, g1col, g2col);
    } else if (blk < 7296) {
        tt_part(dt_g1, dt_g2, W_dtT, 8, 32, 8, 64, blk - 5248, 2048, g1col, g2col);
    } else if (blk < 9344) {
        const int i = (blk - 7296) * 256 + threadIdx.x;   // over BL*EE/4
        float4 v = ((const float4*)x)[i];
        ushort4 o;
        o.x = f2bf(v.x); o.y = f2bf(v.y); o.z = f2bf(v.z); o.w = f2bf(v.w);
        ((ushort4*)xb)[i] = o;
    } else {
        const int idx = (blk - 9344) * 256 + threadIdx.x; // over DIN*NST
        const int d = idx >> 4, n = idx & 15;
        A2t[n * DIN + d] = -expf(A_log[idx]);
    }
}

// ---------------- bf16 MFMA GEMM (templated BN / BK / output mode) ----------------
// C = A[M,K] @ Bt[N,K]^T. A/Bt row-major bf16 (row stride K). BM=128.
// BK=64: halves barrier drains per MFMA vs BK=32 (m97 stall).
// XOR swizzle on 16B k-slots: LDS pos s holds global slot s^((r>>1)&(SLOT-1))
// -> ds_read_b128 2-way (free, m136), global_load_lds lane-contiguity kept.
// Split-K: blockIdx.z picks K-chunk + output plane (czstride).
// OUT: 0 = f32 store, 1 = bf16, 2 = softplus+bf16.
typedef __attribute__((ext_vector_type(8))) short bf16x8;
typedef __attribute__((ext_vector_type(4))) float floatx4;

template<int BN, int BK, int OUT>
__global__ __launch_bounds__(256) void gemm_bf16(
    const u16* __restrict__ A, const u16* __restrict__ Bt, void* __restrict__ Cout,
    int K, int ldc, int kchunk, size_t czstride)
{
    constexpr int BM   = 128;
    constexpr int NT   = BN / 32;          // n-tiles per wave
    constexpr int SLOT = BK / 8;           // 16B slots per LDS row
    constexpr int CR   = 64 / SLOT;        // rows per copy instruction
    constexpr int NACH = BM / CR / 4;      // A copies per wave
    constexpr int NBCH = BN / CR / 4;      // B copies per wave
    constexpr int KG   = BK / 32;          // MFMA k-groups per step
    __shared__ u16 As[BM * BK];
    __shared__ u16 Bs[BN * BK];

    const int tid  = threadIdx.x;
    const int w    = tid >> 6;
    const int lane = tid & 63;
    const int wm   = w & 1, wn = w >> 1;
    const int row0 = blockIdx.y * BM;
    const int col0 = blockIdx.x * BN;
    const int kbeg = blockIdx.z * kchunk;

    const int srow = lane / SLOT;
    const int kqp  = lane % SLOT;
    const u16* ga[NACH]; u16* la[NACH];
    #pragma unroll
    for (int i = 0; i < NACH; ++i) {
        const int c  = w * NACH + i;
        const int r  = c * CR + srow;
        const int kq = kqp ^ ((r >> 1) & (SLOT - 1));
        ga[i] = A + (size_t)(row0 + r) * K + kbeg + kq * 8;
        la[i] = &As[c * CR * BK];
    }
    const u16* gb[NBCH]; u16* lb[NBCH];
    #pragma unroll
    for (int i = 0; i < NBCH; ++i) {
        const int c  = w * NBCH + i;
        const int r  = c * CR + srow;
        const int kq = kqp ^ ((r >> 1) & (SLOT - 1));
        gb[i] = Bt + (size_t)(col0 + r) * K + kbeg + kq * 8;
        lb[i] = &Bs[c * CR * BK];
    }

    const int q = lane >> 4, l15 = lane & 15;
    int a_off[4][KG], b_off[NT][KG];
    #pragma unroll
    for (int mt = 0; mt < 4; ++mt) {
        const int r = wm * 64 + mt * 16 + l15;
        const int m = (r >> 1) & (SLOT - 1);
        #pragma unroll
        for (int kk = 0; kk < KG; ++kk)
            a_off[mt][kk] = r * BK + ((kk * 4 + q) ^ m) * 8;
    }
    #pragma unroll
    for (int nt = 0; nt < NT; ++nt) {
        const int r = wn * (BN / 2) + nt * 16 + l15;
        const int m = (r >> 1) & (SLOT - 1);
        #pragma unroll
        for (int kk = 0; kk < KG; ++kk)
            b_off[nt][kk] = r * BK + ((kk * 4 + q) ^ m) * 8;
    }

    floatx4 acc[4][NT];
    #pragma unroll
    for (int mt = 0; mt < 4; ++mt)
        #pragma unroll
        for (int nt = 0; nt < NT; ++nt)
            acc[mt][nt] = (floatx4){0.f, 0.f, 0.f, 0.f};

    for (int k0 = 0; k0 < kchunk; k0 += BK) {
        #pragma unroll
        for (int i = 0; i < NACH; ++i) { async_copy16(ga[i], la[i]); ga[i] += BK; }
        #pragma unroll
        for (int i = 0; i < NBCH; ++i) { async_copy16(gb[i], lb[i]); gb[i] += BK; }
        __syncthreads();   // drains vmcnt -> tiles ready

        bf16x8 af[4][KG], bfv[NT][KG];
        #pragma unroll
        for (int mt = 0; mt < 4; ++mt)
            #pragma unroll
            for (int kk = 0; kk < KG; ++kk)
                af[mt][kk] = *(const bf16x8*)&As[a_off[mt][kk]];
        #pragma unroll
        for (int nt = 0; nt < NT; ++nt)
            #pragma unroll
            for (int kk = 0; kk < KG; ++kk)
                bfv[nt][kk] = *(const bf16x8*)&Bs[b_off[nt][kk]];

        #pragma unroll
        for (int kk = 0; kk < KG; ++kk)
            #pragma unroll
            for (int mt = 0; mt < 4; ++mt)
                #pragma unroll
                for (int nt = 0; nt < NT; ++nt)
                    acc[mt][nt] = __builtin_amdgcn_mfma_f32_16x16x32_bf16(
                        af[mt][kk], bfv[nt][kk], acc[mt][nt], 0, 0, 0);

        __syncthreads();   // reads done before next stage overwrites
    }

    // epilogue: C/D layout col=lane&15, row=(lane>>4)*4+reg  [verified m89/m91]
    #pragma unroll
    for (int mt = 0; mt < 4; ++mt) {
        const int row = row0 + wm * 64 + mt * 16 + q * 4;
        #pragma unroll
        for (int nt = 0; nt < NT; ++nt) {
            const int col = col0 + wn * (BN / 2) + nt * 16 + l15;
            #pragma unroll
            for (int r = 0; r < 4; ++r) {
                const float v = acc[mt][nt][r];
                if constexpr (OUT == 0) {
                    ((float*)Cout)[(size_t)blockIdx.z * czstride + (size_t)(row + r) * ldc + col] = v;
                } else if constexpr (OUT == 1) {
                    ((u16*)Cout)[(size_t)(row + r) * ldc + col] = f2bf(v);
                } else {
                    ((u16*)Cout)[(size_t)(row + r) * ldc + col] = f2bf(softplusf(v));
                }
            }
        }
    }
}

// reduce GEMM2 split-K partials: dtBC[row][col<96] = sum_z part[z][row][col];
// also emit dt_un (cols 0..63) as bf16 for GEMM3.
__global__ __launch_bounds__(256) void reduce_dtbc(
    const float* __restrict__ part, float* __restrict__ dtBC, u16* __restrict__ dtun_b)
{
    int idx = blockIdx.x * 256 + threadIdx.x;
    if (idx >= BL * 96) return;
    const int row = idx / 96;
    const int col = idx - row * 96;
    float s = 0.f;
    #pragma unroll
    for (int z = 0; z < 16; ++z)
        s += part[(size_t)z * BL * 128 + (size_t)row * 128 + col];
    dtBC[idx] = s;
    if (col < 64) dtun_b[(size_t)row * 64 + col] = f2bf(s);
}

// reduce GEMM4 split-K partials (z=2) -> f32 d_out, float4-wide
__global__ __launch_bounds__(256) void reduce_out(
    const float* __restrict__ part, float* __restrict__ out)
{
    const int idx = blockIdx.x * 256 + threadIdx.x;   // over BL*EE/4
    const float4 a = ((const float4*)part)[idx];
    const float4 b = ((const float4*)part)[idx + BL * EE / 4];
    float4 o;
    o.x = a.x + b.x; o.y = a.y + b.y; o.z = a.z + b.z; o.w = a.w + b.w;
    ((float4*)out)[idx] = o;
}

// ---------------- conv (depthwise K=4, SAME pad_lo=1) + SiLU + gate, bf16, 8-wide ----------------
typedef __attribute__((ext_vector_type(8))) unsigned short ushortx8;

__global__ __launch_bounds__(256) void conv_gate(
    const u16* __restrict__ xzb, const float* __restrict__ filt,
    const float* __restrict__ bias, u16* __restrict__ yb)
{
    int idx = blockIdx.x * blockDim.x + threadIdx.x;   // over BL*DIN/8
    if (idx >= BL * DIN / 8) return;
    const int d  = (idx % (DIN / 8)) * 8;
    const int bt = idx / (DIN / 8);
    const int b  = bt >> 10;
    const int t  = bt & 1023;

    float acc[8];
    #pragma unroll
    for (int j = 0; j < 8; ++j) acc[j] = bias[d + j];
    #pragma unroll
    for (int k = 0; k < 4; ++k) {
        const int tt = t + k - 1;
        if ((unsigned)tt < (unsigned)LL) {
            const ushortx8 xc = *(const ushortx8*)(xzb + (size_t)(b * LL + tt) * (2 * DIN) + d);
            #pragma unroll
            for (int j = 0; j < 8; ++j)
                acc[j] = fmaf(bf2f(xc[j]), filt[(size_t)k * DIN + d + j], acc[j]);
        }
    }
    const ushortx8 z = *(const ushortx8*)(xzb + (size_t)bt * (2 * DIN) + DIN + d);
    ushortx8 o;
    #pragma unroll
    for (int j = 0; j < 8; ++j)
        o[j] = f2bf(acc[j] / (1.f + __expf(-acc[j])) * bf2f(z[j]));
    *(ushortx8*)(yb + (size_t)bt * DIN + d) = o;
}

// ---------------- SSM chunked scan (dt and u in bf16; NCHUNK=32) ----------------
__global__ __launch_bounds__(256) void scan_phase_a(
    const u16* __restrict__ dt, const u16* __restrict__ u,
    const float* __restrict__ dtBC, const float* __restrict__ A2t,
    float* __restrict__ hend, float* __restrict__ sdtbuf)
{
    const int d = blockIdx.x * 256 + threadIdx.x;
    const int c = blockIdx.y;
    const int b = blockIdx.z;

    __shared__ float Bs[CLEN][NST];
    for (int e = threadIdx.x; e < CLEN * NST; e += 256) {
        const int tl = e >> 4, n = e & 15;
        Bs[tl][n] = dtBC[(size_t)(b * LL + c * CLEN + tl) * 96 + 64 + n];
    }
    __syncthreads();

    float A2r[NST];
    #pragma unroll
    for (int n = 0; n < NST; ++n) A2r[n] = A2t[n * DIN + d];

    float h[NST] = {};
    float sdt = 0.f;
    const size_t tbase = (size_t)(b * LL + c * CLEN) * DIN + d;
    for (int tl = 0; tl < CLEN; ++tl) {
        const float dtv = bf2f(dt[tbase + (size_t)tl * DIN]);
        const float uv  = bf2f(u [tbase + (size_t)tl * DIN]);
        sdt += dtv;
        const float cu = dtv * uv;
        #pragma unroll
        for (int n = 0; n < NST; ++n) {
            const float a = __expf(A2r[n] * dtv);
            h[n] = fmaf(a, h[n], cu * Bs[tl][n]);
        }
    }
    const int cb = b * NCHUNK + c;
    #pragma unroll
    for (int n = 0; n < NST; ++n)
        hend[((size_t)cb * NST + n) * DIN + d] = h[n];
    sdtbuf[(size_t)cb * DIN + d] = sdt;
}

__global__ __launch_bounds__(256) void scan_phase_b(
    const float* __restrict__ A2t, const float* __restrict__ sdtbuf,
    float* __restrict__ hcarry)
{
    const int idx = blockIdx.x * 256 + threadIdx.x;  // b*32768 + n*2048 + d
    if (idx >= BB_ * NST * DIN) return;
    const int d = idx & (DIN - 1);
    const int n = (idx >> 11) & 15;
    const int b = idx >> 15;
    const float A2 = A2t[n * DIN + d];
    float h = 0.f;
    for (int c = 0; c < NCHUNK; ++c) {
        const int cb = b * NCHUNK + c;
        const size_t off = ((size_t)cb * NST + n) * DIN + d;
        const float he = hcarry[off];
        const float pa = __expf(A2 * sdtbuf[(size_t)cb * DIN + d]);
        hcarry[off] = h;
        h = fmaf(pa, h, he);
    }
}

__global__ __launch_bounds__(256) void scan_phase_c(
    const u16* __restrict__ dt, const u16* __restrict__ u,
    const float* __restrict__ dtBC, const float* __restrict__ A2t,
    const float* __restrict__ hinit, const float* __restrict__ Dp,
    u16* __restrict__ ysb)
{
    const int d = blockIdx.x * 256 + threadIdx.x;
    const int c = blockIdx.y;
    const int b = blockIdx.z;

    __shared__ float Bs[CLEN][NST];
    __shared__ float Cs[CLEN][NST];
    for (int e = threadIdx.x; e < CLEN * NST; e += 256) {
        const int tl = e >> 4, n = e & 15;
        const size_t base = (size_t)(b * LL + c * CLEN + tl) * 96;
        Bs[tl][n] = dtBC[base + 64 + n];
        Cs[tl][n] = dtBC[base + 80 + n];
    }
    __syncthreads();

    float A2r[NST], h[NST];
    const int cb = b * NCHUNK + c;
    #pragma unroll
    for (int n = 0; n < NST; ++n) {
        A2r[n] = A2t[n * DIN + d];
        h[n]   = hinit[((size_t)cb * NST + n) * DIN + d];
    }
    const float Dv = Dp[d];

    const size_t tbase = (size_t)(b * LL + c * CLEN) * DIN + d;
    for (int tl = 0; tl < CLEN; ++tl) {
        const float dtv = bf2f(dt[tbase + (size_t)tl * DIN]);
        const float uv  = bf2f(u [tbase + (size_t)tl * DIN]);
        const float cu = dtv * uv;
        float yacc = 0.f;
        #pragma unroll
        for (int n = 0; n < NST; ++n) {
            const float a = __expf(A2r[n] * dtv);
            h[n] = fmaf(a, h[n], cu * Bs[tl][n]);
            yacc = fmaf(h[n], Cs[tl][n], yacc);
        }
        ysb[tbase + (size_t)tl * DIN] = f2bf(fmaf(Dv, uv, yacc));
    }
}

// ---------------- launcher ----------------
extern "C" void kernel_launch(void* const* d_in, const int* in_sizes, int n_in,
                              void* d_out, int out_size, void* d_ws, size_t ws_size,
                              hipStream_t stream)
{
    const float* x       = (const float*)d_in[0];
    const float* in_g1   = (const float*)d_in[1];
    const float* in_g2   = (const float*)d_in[2];
    const float* x_g1    = (const float*)d_in[3];
    const float* x_g2    = (const float*)d_in[4];
    const float* dt_g1   = (const float*)d_in[5];
    const float* dt_g2   = (const float*)d_in[6];
    const float* out_g1  = (const float*)d_in[7];
    const float* out_g2  = (const float*)d_in[8];
    const float* filt    = (const float*)d_in[9];
    const float* bias    = (const float*)d_in[10];
    const float* A_log   = (const float*)d_in[11];
    const float* Dp      = (const float*)d_in[12];

    float* ws     = (float*)d_ws;
    u16*   W_inT  = (u16*)(ws + OFF_WINT);
    u16*   W_outT = (u16*)(ws + OFF_WOUTT);
    u16*   W_xT   = (u16*)(ws + OFF_WXT);
    u16*   W_dtT  = (u16*)(ws + OFF_WDTT);
    float* A2t    = ws + OFF_A2T;
    u16*   xb     = (u16*)(ws + OFF_XB);
    u16*   xzb    = (u16*)(ws + OFF_XZB);
    u16*   yb     = (u16*)(ws + OFF_YB);
    float* part   = ws + OFF_PART;
    float* dtBC   = ws + OFF_DTBC;
    u16*   dtun_b = (u16*)(ws + OFF_DTUNB);
    u16*   dtb    = (u16*)(ws + OFF_DTB);
    u16*   ysb    = (u16*)(ws + OFF_YSB);
    float* hc     = ws + OFF_HC;
    float* sdt    = ws + OFF_SDT;

    // 1) all prep in one launch: W_inT, W_outT, W_xT, W_dtT, x->bf16, A2t
    mega_prep<<<9472, 256, 0, stream>>>(
        in_g1, in_g2, W_inT, out_g1, out_g2, W_outT,
        x_g1, x_g2, W_xT, dt_g1, dt_g2, W_dtT,
        x, xb, A_log, A2t);

    // 2) xz = x @ W_in  (M=2048, N=4096, K=1024), BK=64 -> bf16
    gemm_bf16<128, 64, 1><<<dim3(32, 16, 1), 256, 0, stream>>>(
        xb, W_inT, xzb, EE, 4096, EE, 0);

    // 3) y = silu(conv(xc) + bias) * z  -> bf16, 8-wide
    conv_gate<<<(BL * DIN / 8 + 255) / 256, 256, 0, stream>>>(xzb, filt, bias, yb);

    // 4) dtBC partials = y @ W_x (M=2048, N=128, K=2048), split-K z=16, BK=64
    gemm_bf16<128, 64, 0><<<dim3(1, 16, 16), 256, 0, stream>>>(
        yb, W_xT, part, DIN, 128, 128, (size_t)BL * 128);
    reduce_dtbc<<<(BL * 96 + 255) / 256, 256, 0, stream>>>(part, dtBC, dtun_b);

    // 5) dt = softplus(dt_un @ W_dt) (M=2048, N=2048, K=64) single-step -> bf16
    gemm_bf16<128, 64, 2><<<dim3(16, 16, 1), 256, 0, stream>>>(
        dtun_b, W_dtT, dtb, 64, DIN, 64, 0);

    // 6) SSM chunked scan, NCHUNK=32 (512 blocks = 2/CU)
    scan_phase_a<<<dim3(DIN / 256, NCHUNK, BB_), 256, 0, stream>>>(dtb, yb, dtBC, A2t, hc, sdt);
    scan_phase_b<<<(BB_ * NST * DIN) / 256, 256, 0, stream>>>(A2t, sdt, hc);
    scan_phase_c<<<dim3(DIN / 256, NCHUNK, BB_), 256, 0, stream>>>(dtb, yb, dtBC, A2t, hc, Dp, ysb);

    // 7) out = ssm @ W_out (M=2048, N=1024, K=2048), split-K z=2 (512 blocks = 2/CU)
    gemm_bf16<64, 64, 0><<<dim3(16, 16, 2), 256, 0, stream>>>(
        ysb, W_outT, part, DIN, EE, EE, (size_t)BL * EE);
    reduce_out<<<(BL * EE / 4) / 256, 256, 0, stream>>>(part, (float*)d_out);
}